// Round 12
// baseline (4650.529 us; speedup 1.0000x reference)
//
#include <hip/hip_runtime.h>
#include <hip/hip_bf16.h>
#include <cstddef>
#include <cstdint>

// Problem constants
#define BB 8
#define SS 1024
#define EE 512
#define DD 1024
#define LL 8
#define HH 16
#define HD 64
#define ROT 32
#define FF 4096
#define FUSED 11264   // 3*D + 2*FF
#define NTOK 8192     // B*S
#define QKVW 3072     // width of qkv projection buffer
#define CATW 5120     // attn-out (1024) + gated-ff (4096) concat width

using u16 = unsigned short;
typedef __attribute__((ext_vector_type(8))) __bf16 bf16x8;
typedef __attribute__((ext_vector_type(4))) float f32x4;
typedef __attribute__((ext_vector_type(4))) unsigned short u16x4;
typedef __attribute__((ext_vector_type(8))) unsigned short u16x8;

typedef const __attribute__((address_space(1))) void gas_t;
typedef __attribute__((address_space(3))) void las_t;

#define VMCNT8 asm volatile("s_waitcnt vmcnt(8)" ::: "memory")
#define VMCNT0 asm volatile("s_waitcnt vmcnt(0)" ::: "memory")

__device__ __forceinline__ void gld16(const void* g, void* l) {
  __builtin_amdgcn_global_load_lds((gas_t*)g, (las_t*)l, 16, 0, 0);
}

__device__ __forceinline__ float bf2f(u16 u) {
  union { unsigned int i; float f; } v; v.i = ((unsigned int)u) << 16; return v.f;
}
__device__ __forceinline__ u16 f2bf(float f) {
  union { float f; unsigned int i; } v; v.f = f;
  unsigned int u = v.i;
  unsigned int r = u + 0x7FFFu + ((u >> 16) & 1u);
  return (u16)(r >> 16);
}
__device__ __forceinline__ float gelu_f(float x) {
  return x * 0.5f * (1.0f + erff(x / 1.41421f));
}
__device__ __forceinline__ float silu_f(float x) {
  return x / (1.0f + __expf(-x));
}

// ---------------------------------------------------------------------------
// Generic bf16 B^T GEMM: C[M,N] (+)= A[M,K] * W[N,K]^T (+ bias[N])
// 128x128 tile, BK=64, 4 waves (2x2). Counted-vmcnt two-barrier K-loop
// (R8 structure — verified local optimum; phase-splitting regressed in R9).
// ---------------------------------------------------------------------------
template <int ACCUM, int OUTBF16>
__global__ __launch_bounds__(256, 2) void gemm_bt(
    const u16* __restrict__ A, const u16* __restrict__ W,
    const float* __restrict__ bias, void* __restrict__ Cp,
    int M, int N, int K) {
  __shared__ __align__(16) u16 As[2][128 * 64];
  __shared__ __align__(16) u16 Bs[2][128 * 64];
  const int tid = threadIdx.x;
  const int w = tid >> 6, lane = tid & 63;
  const int m0 = blockIdx.y * 128, n0 = blockIdx.x * 128;
  const int wm = w >> 1, wn = w & 1;

  f32x4 acc[4][4] = {};

  auto stage = [&](int buf, int k0) {
#pragma unroll
    for (int i = 0; i < 4; i++) {
      const int c = w + i * 4;                 // 1KB chunk id, 0..15
      const int r = c * 8 + (lane >> 3);       // tile row (128B rows)
      const int colb = ((lane & 7) << 4) ^ ((r & 7) << 4);  // pre-swizzled src col
      gld16(A + (size_t)(m0 + r) * K + k0 + (colb >> 1), &As[buf][c * 512]);
      gld16(W + (size_t)(n0 + r) * K + k0 + (colb >> 1), &Bs[buf][c * 512]);
    }
  };

  const int nt = K >> 6;
  stage(0, 0);

  for (int t = 0; t < nt; t++) {
    const int cur = t & 1;
    if (t + 1 < nt) {
      stage(cur ^ 1, (t + 1) << 6);
      VMCNT8;
    } else {
      VMCNT0;
    }
    __builtin_amdgcn_s_barrier();   // buf[cur] published (all waves)

    bf16x8 av0[4], bv0[4], av1[4], bv1[4];
#pragma unroll
    for (int m = 0; m < 4; m++) {
      const int row = wm * 64 + m * 16 + (lane & 15);
      const int sw = (row & 7) << 4;
      av0[m] = *(const bf16x8*)((const char*)As[cur] + row * 128 + ((((lane >> 4) << 4)) ^ sw));
      av1[m] = *(const bf16x8*)((const char*)As[cur] + row * 128 + ((64 + ((lane >> 4) << 4)) ^ sw));
    }
#pragma unroll
    for (int n = 0; n < 4; n++) {
      const int row = wn * 64 + n * 16 + (lane & 15);
      const int sw = (row & 7) << 4;
      bv0[n] = *(const bf16x8*)((const char*)Bs[cur] + row * 128 + ((((lane >> 4) << 4)) ^ sw));
      bv1[n] = *(const bf16x8*)((const char*)Bs[cur] + row * 128 + ((64 + ((lane >> 4) << 4)) ^ sw));
    }
    __builtin_amdgcn_s_setprio(1);
#pragma unroll
    for (int m = 0; m < 4; m++)
#pragma unroll
      for (int n = 0; n < 4; n++)
        acc[m][n] = __builtin_amdgcn_mfma_f32_16x16x32_bf16(av0[m], bv0[n], acc[m][n], 0, 0, 0);
#pragma unroll
    for (int m = 0; m < 4; m++)
#pragma unroll
      for (int n = 0; n < 4; n++)
        acc[m][n] = __builtin_amdgcn_mfma_f32_16x16x32_bf16(av1[m], bv1[n], acc[m][n], 0, 0, 0);
    __builtin_amdgcn_s_setprio(0);
    __builtin_amdgcn_s_barrier();   // buf[cur] free for overwrite next iter
  }

  const int rowb0 = m0 + wm * 64 + ((lane >> 4) << 2);
  const int colb0 = n0 + wn * 64 + (lane & 15);
#pragma unroll
  for (int n = 0; n < 4; n++) {
    const int col = colb0 + n * 16;
    const float bn = bias ? bias[col] : 0.0f;
#pragma unroll
    for (int m = 0; m < 4; m++) {
#pragma unroll
      for (int r = 0; r < 4; r++) {
        const size_t idx = (size_t)(rowb0 + m * 16 + r) * N + col;
        const float v = acc[m][n][r] + bn;
        if (ACCUM) {
          ((float*)Cp)[idx] += v;
        } else if (OUTBF16) {
          ((u16*)Cp)[idx] = f2bf(v);
        } else {
          ((float*)Cp)[idx] = v;
        }
      }
    }
  }
}

// ---------------------------------------------------------------------------
// Merged qkv+ffg 256x256-tile bf16 B^T GEMM (8 waves 2Mx4N, BK=64, 128KB LDS
// dbuf, counted-vmcnt two-barrier pipeline — R8-verified K-loop, unchanged).
// Weight rows [0,3072) = qkv; rows [3072,11264) = ff/gate interleaved per
// 16-col group. Epilogue branches on wave-uniform n0:
//   n0 < 3072  -> plain bf16 write into projq (stride QKVW)
//   n0 >= 3072 -> gated ff*gelu(gate) write into acat cols [1024,5120)
// ---------------------------------------------------------------------------
__global__ __launch_bounds__(512, 2) void gemm_qf256(
    const u16* __restrict__ A, const u16* __restrict__ W,
    u16* __restrict__ projq, u16* __restrict__ acat, int M, int K) {
  __shared__ __align__(16) u16 As[2][256 * 64];   // 64 KB
  __shared__ __align__(16) u16 Bs[2][256 * 64];   // 64 KB
  const int tid = threadIdx.x;
  const int w = tid >> 6, lane = tid & 63;
  const int m0 = blockIdx.y * 256, n0 = blockIdx.x * 256;
  const int wm = w >> 2, wn = w & 3;   // 2 x 4 wave grid

  f32x4 acc[8][4] = {};

  auto stage = [&](int buf, int k0) {
#pragma unroll
    for (int i = 0; i < 4; i++) {
      const int c = w + i * 8;                 // 1KB chunk id, 0..31
      const int r = c * 8 + (lane >> 3);       // tile row 0..255 (128B rows)
      const int colb = ((lane & 7) << 4) ^ ((r & 7) << 4);
      gld16(A + (size_t)(m0 + r) * K + k0 + (colb >> 1), &As[buf][c * 512]);
      gld16(W + (size_t)(n0 + r) * K + k0 + (colb >> 1), &Bs[buf][c * 512]);
    }
  };

  const int nt = K >> 6;
  stage(0, 0);

  for (int t = 0; t < nt; t++) {
    const int cur = t & 1;
    if (t + 1 < nt) {
      stage(cur ^ 1, (t + 1) << 6);
      VMCNT8;
    } else {
      VMCNT0;
    }
    __builtin_amdgcn_s_barrier();

    // ks=0
    {
      bf16x8 av0[8], bv0[4];
#pragma unroll
      for (int m = 0; m < 8; m++) {
        const int row = wm * 128 + m * 16 + (lane & 15);
        const int cb = (((lane >> 4) << 4)) ^ ((row & 7) << 4);
        av0[m] = *(const bf16x8*)((const char*)As[cur] + row * 128 + cb);
      }
#pragma unroll
      for (int n = 0; n < 4; n++) {
        const int row = wn * 64 + n * 16 + (lane & 15);
        const int cb = (((lane >> 4) << 4)) ^ ((row & 7) << 4);
        bv0[n] = *(const bf16x8*)((const char*)Bs[cur] + row * 128 + cb);
      }
      __builtin_amdgcn_s_setprio(1);
#pragma unroll
      for (int m = 0; m < 8; m++)
#pragma unroll
        for (int n = 0; n < 4; n++)
          acc[m][n] = __builtin_amdgcn_mfma_f32_16x16x32_bf16(av0[m], bv0[n], acc[m][n], 0, 0, 0);
      __builtin_amdgcn_s_setprio(0);
    }
    // ks=1
    {
      bf16x8 av1[8], bv1[4];
#pragma unroll
      for (int m = 0; m < 8; m++) {
        const int row = wm * 128 + m * 16 + (lane & 15);
        const int cb = (64 + ((lane >> 4) << 4)) ^ ((row & 7) << 4);
        av1[m] = *(const bf16x8*)((const char*)As[cur] + row * 128 + cb);
      }
#pragma unroll
      for (int n = 0; n < 4; n++) {
        const int row = wn * 64 + n * 16 + (lane & 15);
        const int cb = (64 + ((lane >> 4) << 4)) ^ ((row & 7) << 4);
        bv1[n] = *(const bf16x8*)((const char*)Bs[cur] + row * 128 + cb);
      }
      __builtin_amdgcn_s_setprio(1);
#pragma unroll
      for (int m = 0; m < 8; m++)
#pragma unroll
        for (int n = 0; n < 4; n++)
          acc[m][n] = __builtin_amdgcn_mfma_f32_16x16x32_bf16(av1[m], bv1[n], acc[m][n], 0, 0, 0);
      __builtin_amdgcn_s_setprio(0);
    }
    __builtin_amdgcn_s_barrier();
  }

  const int rowb0 = m0 + wm * 128 + ((lane >> 4) << 2);
  if (n0 >= QKVW) {
    // gated ff/gate pairs -> acat cols [1024, 5120)
    const int ocol0 = DD + ((n0 - QKVW) >> 1);
#pragma unroll
    for (int n = 0; n < 4; n += 2) {
      const int outcol = ocol0 + wn * 32 + ((n >> 1) << 4) + (lane & 15);
#pragma unroll
      for (int m = 0; m < 8; m++)
#pragma unroll
        for (int r = 0; r < 4; r++) {
          const float fv = acc[m][n][r];
          const float gv = acc[m][n + 1][r];
          acat[(size_t)(rowb0 + m * 16 + r) * CATW + outcol] = f2bf(fv * gelu_f(gv));
        }
    }
  } else {
    // plain bf16 -> projq (stride QKVW)
    const int colb0 = n0 + wn * 64 + (lane & 15);
#pragma unroll
    for (int n = 0; n < 4; n++) {
      const int col = colb0 + n * 16;
#pragma unroll
      for (int m = 0; m < 8; m++)
#pragma unroll
        for (int r = 0; r < 4; r++)
          projq[(size_t)(rowb0 + m * 16 + r) * QKVW + col] = f2bf(acc[m][n][r]);
    }
  }
}

// ---------------------------------------------------------------------------
// Flash attention: swapped QK^T (mfma(K,Q) -> C[key][q], col=lane&15=q) so
// each lane holds a full P-row slice for ONE q; tree row-max + 2 shfl_xor.
// T13 defer-max (exact at THR=0). P -> bf16 via v_cvt_pk_bf16_f32 (T12),
// stored as uint2 (b64). Output into acat cols [0,1024), row stride CATW.
// ---------------------------------------------------------------------------
__global__ __launch_bounds__(256, 2) void attn_fwd(
    const u16* __restrict__ qr, const u16* __restrict__ kr,
    const u16* __restrict__ vt, const float* __restrict__ mask,
    u16* __restrict__ acat) {
  __shared__ __align__(16) u16 Ks[2][128 * 64];   // [key][dim], swizzled
  __shared__ __align__(16) u16 Vs[2][64 * 128];   // [d][key], swizzled
  __shared__ __align__(16) u16 Ps[4][16 * 128];   // per-wave P [q][k], XOR-swizzled
  const int tid = threadIdx.x, w = tid >> 6, lane = tid & 63;
  const int g = blockIdx.x;
  const int j = g >> 3;
  const int bh = (g & 7) + ((j >> 4) << 3);
  const int qx = j & 15;
  const int b = bh >> 4;
  const int q0 = qx * 64 + w * 16;
  const u16* Qb = qr + (size_t)bh * SS * HD;
  const u16* Kb = kr + (size_t)bh * SS * HD;
  const u16* Vb = vt + (size_t)bh * HD * SS;
  const float* mb = mask + (size_t)b * SS;
  const int lq = lane & 15, lg = lane >> 4;

  bf16x8 qf0, qf1;
  {
    const int qrow = q0 + lq;
    const u16* qp = Qb + (size_t)qrow * HD + (lg << 3);
    qf0 = *(const bf16x8*)qp;
    qf1 = *(const bf16x8*)(qp + 32);
  }

  float mrun = -1e30f, srun = 0.0f;   // running stats for q-row = lq
  f32x4 acc[4] = {};

  u16* pw = &Ps[w][0];

  auto stage = [&](int buf, int kv0) {
#pragma unroll
    for (int i = 0; i < 4; i++) {
      const int c = w + i * 4;
      {
        const int r = c * 8 + (lane >> 3);
        const int colb = ((lane & 7) << 4) ^ ((r & 7) << 4);
        gld16(Kb + (size_t)(kv0 + r) * HD + (colb >> 1), &Ks[buf][c * 512]);
      }
      {
        const int d = c * 4 + lg;
        const int colb = (lq << 4) ^ ((d & 7) << 4);
        gld16(Vb + (size_t)d * SS + kv0 + (colb >> 1), &Vs[buf][c * 512]);
      }
    }
  };

  stage(0, 0);
  __syncthreads();

  for (int t = 0; t < 8; t++) {
    const int cur = t & 1;
    const int kv0 = t * 128;
    if (t < 7) stage(cur ^ 1, kv0 + 128);

    // swapped QK^T: p[blk][r] = P[key = blk*16 + lg*4 + r][q = lq]
    f32x4 p[8];
    __builtin_amdgcn_s_setprio(1);
#pragma unroll
    for (int blk = 0; blk < 8; blk++) {
      const int row = blk * 16 + lq;
      const int swz = (row & 7) << 4;
      const bf16x8 k0v = *(const bf16x8*)((const char*)Ks[cur] + row * 128 + (((lg << 4)) ^ swz));
      const bf16x8 k1v = *(const bf16x8*)((const char*)Ks[cur] + row * 128 + ((64 + (lg << 4)) ^ swz));
      f32x4 z = {};
      p[blk] = __builtin_amdgcn_mfma_f32_16x16x32_bf16(k0v, qf0, z, 0, 0, 0);
      p[blk] = __builtin_amdgcn_mfma_f32_16x16x32_bf16(k1v, qf1, p[blk], 0, 0, 0);
    }
    __builtin_amdgcn_s_setprio(0);

#pragma unroll
    for (int blk = 0; blk < 8; blk++) {
      const float4 m4 = *(const float4*)(mb + kv0 + blk * 16 + (lg << 2));
      p[blk][0] = p[blk][0] * (1.0f / 64.0f) + m4.x;
      p[blk][1] = p[blk][1] * (1.0f / 64.0f) + m4.y;
      p[blk][2] = p[blk][2] * (1.0f / 64.0f) + m4.z;
      p[blk][3] = p[blk][3] * (1.0f / 64.0f) + m4.w;
    }

    // tree row-max (shallow dependency chains)
    float mr[8];
#pragma unroll
    for (int blk = 0; blk < 8; blk++)
      mr[blk] = fmaxf(fmaxf(p[blk][0], p[blk][1]), fmaxf(p[blk][2], p[blk][3]));
    float mrow = fmaxf(fmaxf(fmaxf(mr[0], mr[1]), fmaxf(mr[2], mr[3])),
                       fmaxf(fmaxf(mr[4], mr[5]), fmaxf(mr[6], mr[7])));
    mrow = fmaxf(mrow, __shfl_xor(mrow, 16));
    mrow = fmaxf(mrow, __shfl_xor(mrow, 32));

    if (__any(mrow > mrun)) {       // T13 defer-max (exact at THR=0)
      const float mn = fmaxf(mrun, mrow);
      const float facq = __expf(mrun - mn);
      mrun = mn;
      srun *= facq;
      float fac[4];
#pragma unroll
      for (int r = 0; r < 4; r++)
        fac[r] = __shfl(facq, (lane & 48) | ((lg << 2) + r));
#pragma unroll
      for (int dblk = 0; dblk < 4; dblk++)
#pragma unroll
        for (int r = 0; r < 4; r++) acc[dblk][r] *= fac[r];
    }

    // exp + 4-way parallel sum + cvt_pk bf16 pack (T12)
    float rs0 = 0.0f, rs1 = 0.0f, rs2 = 0.0f, rs3 = 0.0f;
#pragma unroll
    for (int blk = 0; blk < 8; blk++) {
      const float e0 = __expf(p[blk][0] - mrun);
      const float e1 = __expf(p[blk][1] - mrun);
      const float e2 = __expf(p[blk][2] - mrun);
      const float e3 = __expf(p[blk][3] - mrun);
      rs0 += e0; rs1 += e1; rs2 += e2; rs3 += e3;
      unsigned int r01, r23;
      asm("v_cvt_pk_bf16_f32 %0, %1, %2" : "=v"(r01) : "v"(e0), "v"(e1));
      asm("v_cvt_pk_bf16_f32 %0, %1, %2" : "=v"(r23) : "v"(e2), "v"(e3));
      uint2 pk; pk.x = r01; pk.y = r23;
      *(uint2*)(pw + ((lq * 128 + blk * 16 + (lg << 2)) ^ ((lq & 7) << 3))) = pk;
    }
    float rs = (rs0 + rs1) + (rs2 + rs3);
    rs += __shfl_xor(rs, 16);
    rs += __shfl_xor(rs, 32);
    srun += rs;

    bf16x8 pa[4];
#pragma unroll
    for (int ks = 0; ks < 4; ks++)
      pa[ks] = *(const bf16x8*)(pw + ((lq * 128 + ks * 32 + (lg << 3)) ^ ((lq & 7) << 3)));

    __builtin_amdgcn_s_setprio(1);
#pragma unroll
    for (int dblk = 0; dblk < 4; dblk++) {
      const int drow = dblk * 16 + lq;
      const int swz = (drow & 7) << 4;
#pragma unroll
      for (int ks = 0; ks < 4; ks++) {
        const bf16x8 vv = *(const bf16x8*)((const char*)Vs[cur] + drow * 256 + ((ks * 64 + (lg << 4)) ^ swz));
        acc[dblk] = __builtin_amdgcn_mfma_f32_16x16x32_bf16(pa[ks], vv, acc[dblk], 0, 0, 0);
      }
    }
    __builtin_amdgcn_s_setprio(0);

    __syncthreads();
  }

  float sden[4];
#pragma unroll
  for (int r = 0; r < 4; r++)
    sden[r] = __shfl(srun, (lane & 48) | ((lg << 2) + r));
#pragma unroll
  for (int dblk = 0; dblk < 4; dblk++)
#pragma unroll
    for (int r = 0; r < 4; r++) {
      const int sq = q0 + (lg << 2) + r;
      const int d = dblk * 16 + lq;
      acat[((size_t)b * SS + sq) * CATW + (bh & 15) * HD + d] = f2bf(acc[dblk][r] / sden[r]);
    }
}

// ---------------------------------------------------------------------------
// LayerNorm (+ optional AdaLN modulation) over D=1024, one block per row.
// ---------------------------------------------------------------------------
__global__ __launch_bounds__(256) void ln_mod(
    const float* __restrict__ x, const float* __restrict__ lw,
    const float* __restrict__ lb, const float* __restrict__ sb,
    u16* __restrict__ out) {
  const int row = blockIdx.x, tid = threadIdx.x;
  const float4 v = ((const float4*)(x + (size_t)row * DD))[tid];
  float vv[4] = {v.x, v.y, v.z, v.w};
  float s = vv[0] + vv[1] + vv[2] + vv[3];
  float q = vv[0] * vv[0] + vv[1] * vv[1] + vv[2] * vv[2] + vv[3] * vv[3];
  for (int off = 1; off < 64; off <<= 1) {
    s += __shfl_xor(s, off);
    q += __shfl_xor(q, off);
  }
  __shared__ float red[8];
  const int w = tid >> 6, lane = tid & 63;
  if (lane == 0) { red[w] = s; red[4 + w] = q; }
  __syncthreads();
  s = red[0] + red[1] + red[2] + red[3];
  q = red[4] + red[5] + red[6] + red[7];
  const float mu = s * (1.0f / DD);
  const float inv = rsqrtf(q * (1.0f / DD) - mu * mu + 1e-5f);
  const int b = row >> 10;
  u16x4 o;
#pragma unroll
  for (int j = 0; j < 4; j++) {
    const int d = tid * 4 + j;
    float g = (vv[j] - mu) * inv * lw[d] + lb[d];
    if (sb) g = (1.0f + sb[(size_t)b * 2048 + d]) * g + sb[(size_t)b * 2048 + DD + d];
    o[j] = f2bf(g);
  }
  *(u16x4*)(out + (size_t)row * DD + tid * 4) = o;
}

// Final LayerNorm over E=512, f32 out. One block (128 threads) per row.
__global__ __launch_bounds__(128) void ln_fin(
    const float* __restrict__ x, const float* __restrict__ w_,
    const float* __restrict__ b_, float* __restrict__ out) {
  const int row = blockIdx.x, tid = threadIdx.x;
  const float4 v = ((const float4*)(x + (size_t)row * EE))[tid];
  float vv[4] = {v.x, v.y, v.z, v.w};
  float s = vv[0] + vv[1] + vv[2] + vv[3];
  float q = vv[0] * vv[0] + vv[1] * vv[1] + vv[2] * vv[2] + vv[3] * vv[3];
  for (int off = 1; off < 64; off <<= 1) {
    s += __shfl_xor(s, off);
    q += __shfl_xor(q, off);
  }
  __shared__ float red[4];
  const int w = tid >> 6, lane = tid & 63;
  if (lane == 0) { red[w] = s; red[2 + w] = q; }
  __syncthreads();
  s = red[0] + red[1];
  q = red[2] + red[3];
  const float mu = s * (1.0f / EE);
  const float inv = rsqrtf(q * (1.0f / EE) - mu * mu + 1e-5f);
  float4 o;
  o.x = (vv[0] - mu) * inv * w_[tid * 4 + 0] + b_[tid * 4 + 0];
  o.y = (vv[1] - mu) * inv * w_[tid * 4 + 1] + b_[tid * 4 + 1];
  o.z = (vv[2] - mu) * inv * w_[tid * 4 + 2] + b_[tid * 4 + 2];
  o.w = (vv[3] - mu) * inv * w_[tid * 4 + 3] + b_[tid * 4 + 3];
  ((float4*)(out + (size_t)row * EE))[tid] = o;
}

template <int IA, int OA>
__global__ __launch_bounds__(256) void vec_gemm(
    const float* __restrict__ in, const float* __restrict__ W,
    const float* __restrict__ bias, float* __restrict__ out, int N, int K) {
  const int n = blockIdx.x * 256 + threadIdx.x;
  const int b = blockIdx.y, l = blockIdx.z;
  const float* ir = in + (size_t)b * K;
  const float* wr = W + ((size_t)l * N + n) * K;
  float s = bias[(size_t)l * N + n];
  for (int k = 0; k < K; k += 4) {
    float4 a = *(const float4*)(ir + k);
    const float4 ww = *(const float4*)(wr + k);
    if (IA) { a.x = silu_f(a.x); a.y = silu_f(a.y); a.z = silu_f(a.z); a.w = silu_f(a.w); }
    s += a.x * ww.x + a.y * ww.y + a.z * ww.z + a.w * ww.w;
  }
  if (OA) s = gelu_f(s);
  out[((size_t)l * gridDim.y + b) * N + n] = s;
}

__global__ void time_fourier(const float* __restrict__ times,
                             const float* __restrict__ fw, float* __restrict__ te0) {
  const int j = blockIdx.x * 256 + threadIdx.x;
  const int b = blockIdx.y;
  const float f = 6.28318530717958647692f * times[b] * fw[j];
  te0[(size_t)b * DD + j] = cosf(f);
  te0[(size_t)b * DD + 512 + j] = sinf(f);
}

__global__ void rope_tab(float* __restrict__ st, float* __restrict__ ct) {
  const int s = blockIdx.x;
  const int j = threadIdx.x;
  const int i = j & 15;
  const float inv = powf(10000.0f, -(float)i * (1.0f / 16.0f));
  const float f = (float)s * inv;
  st[s * 32 + j] = bf2f(f2bf(sinf(f)));
  ct[s * 32 + j] = bf2f(f2bf(cosf(f)));
}

__global__ void build_x(const float* __restrict__ a, const float* __restrict__ b,
                        const float* __restrict__ c, const float* __restrict__ m,
                        u16* __restrict__ x) {
  const size_t i4 = ((size_t)blockIdx.x * 256 + threadIdx.x) * 4;
  if (i4 >= (size_t)NTOK * 2048) return;
  const size_t tok = i4 >> 11;
  const int e = (int)(i4 & 2047);
  float4 v;
  if (e < 512)       v = *(const float4*)(a + tok * 512 + e);
  else if (e < 1024) v = *(const float4*)(b + tok * 512 + (e - 512));
  else if (e < 1536) v = *(const float4*)(c + tok * 512 + (e - 1024));
  else { const float mm = m[tok]; v = make_float4(mm, mm, mm, mm); }
  u16x4 o;
  o[0] = f2bf(v.x); o[1] = f2bf(v.y); o[2] = f2bf(v.z); o[3] = f2bf(v.w);
  *(u16x4*)(x + i4) = o;
}

// ---------------------------------------------------------------------------
// Fused RoPE(q,k) + head-split + V-transpose. grid (S/64, H, B), 256 threads.
// V tile in 4 row-groups of [16][72] at base stride 1160 elems: qs-groups land
// at bank phases {0,4,8,12} -> <=2-way conflicts on the transpose reads.
// ---------------------------------------------------------------------------
__global__ __launch_bounds__(256) void rope_all(
    const u16* __restrict__ proj, const float* __restrict__ st,
    const float* __restrict__ ct, u16* __restrict__ q, u16* __restrict__ k,
    u16* __restrict__ v) {
  __shared__ u16 tile[4 * 1160];
  const int tid = threadIdx.x;
  const int s0 = blockIdx.x * 64, h = blockIdx.y, b = blockIdx.z;
  const int sl = tid >> 2, c = tid & 3;
  const int s = s0 + sl;
  const u16* pr = proj + (size_t)(b * SS + s) * QKVW + h * 64;

  {
    const u16x8 a0 = *(const u16x8*)(pr + 2 * DD + c * 16);
    const u16x8 a1 = *(const u16x8*)(pr + 2 * DD + c * 16 + 8);
    u16* trow = &tile[(sl >> 4) * 1160 + (sl & 15) * 72];
    *(u16x8*)&trow[c * 16] = a0;
    *(u16x8*)&trow[c * 16 + 8] = a1;
  }

  {
    const int d0 = c * 16;
    u16 qv[16], kv[16], qo[16], ko[16];
    *(u16x8*)&qv[0] = *(const u16x8*)(pr + d0);
    *(u16x8*)&qv[8] = *(const u16x8*)(pr + d0 + 8);
    *(u16x8*)&kv[0] = *(const u16x8*)(pr + DD + d0);
    *(u16x8*)&kv[8] = *(const u16x8*)(pr + DD + d0 + 8);
    if (c < 2) {
      const int dp = (c ^ 1) * 16;
      u16 qp[16], kp[16];
      *(u16x8*)&qp[0] = *(const u16x8*)(pr + dp);
      *(u16x8*)&qp[8] = *(const u16x8*)(pr + dp + 8);
      *(u16x8*)&kp[0] = *(const u16x8*)(pr + DD + dp);
      *(u16x8*)&kp[8] = *(const u16x8*)(pr + DD + dp + 8);
      const float sg = (c == 0) ? -1.0f : 1.0f;
#pragma unroll
      for (int j = 0; j < 16; j++) {
        const int d = d0 + j;
        const float cs = ct[s * 32 + d], sn = st[s * 32 + d];
        qo[j] = f2bf(bf2f(qv[j]) * cs + sg * bf2f(qp[j]) * sn);
        ko[j] = f2bf(bf2f(kv[j]) * cs + sg * bf2f(kp[j]) * sn);
      }
    } else {
#pragma unroll
      for (int j = 0; j < 16; j++) { qo[j] = qv[j]; ko[j] = kv[j]; }
    }
    u16* qd = q + ((size_t)(b * HH + h) * SS + s) * HD + d0;
    u16* kd = k + ((size_t)(b * HH + h) * SS + s) * HD + d0;
    *(u16x8*)qd = *(u16x8*)&qo[0];
    *(u16x8*)(qd + 8) = *(u16x8*)&qo[8];
    *(u16x8*)kd = *(u16x8*)&ko[0];
    *(u16x8*)(kd + 8) = *(u16x8*)&ko[8];
  }

  __syncthreads();

  {
    const int dl = tid >> 2, gq = tid & 3;   // qs = gq*16
    const u16* tg = &tile[gq * 1160];
    u16x8 o0, o1;
#pragma unroll
    for (int j = 0; j < 8; j++) o0[j] = tg[j * 72 + dl];
#pragma unroll
    for (int j = 0; j < 8; j++) o1[j] = tg[(8 + j) * 72 + dl];
    u16* dst = v + ((size_t)(b * HH + h) * HD + dl) * SS + s0 + gq * 16;
    *(u16x8*)dst = o0;
    *(u16x8*)(dst + 8) = o1;
  }
}

__global__ void cast_bf16(const float* __restrict__ in, u16* __restrict__ out, size_t n4) {
  const size_t i = (size_t)blockIdx.x * 256 + threadIdx.x;
  if (i >= n4) return;
  const float4 v = ((const float4*)in)[i];
  u16x4 o;
  o[0] = f2bf(v.x); o[1] = f2bf(v.y); o[2] = f2bf(v.z); o[3] = f2bf(v.w);
  ((u16x4*)out)[i] = o;
}

// qkv slice of proj_w -> rows [0,3072) of the merged [11264][1024] buffer.
__global__ void cast_q(const float* __restrict__ src, u16* __restrict__ dst) {
  const int i = blockIdx.x * 256 + threadIdx.x;  // over 3072*128
  const int l = blockIdx.y;
  const int r = i >> 7, cb = (i & 127) * 8;
  const float* s = src + ((size_t)l * FUSED + r) * DD + cb;
  const float4 a = *(const float4*)s;
  const float4 b = *(const float4*)(s + 4);
  u16x8 o;
  o[0] = f2bf(a.x); o[1] = f2bf(a.y); o[2] = f2bf(a.z); o[3] = f2bf(a.w);
  o[4] = f2bf(b.x); o[5] = f2bf(b.y); o[6] = f2bf(b.z); o[7] = f2bf(b.w);
  *(u16x8*)(dst + ((size_t)l * FUSED + r) * DD + cb) = o;
}

// ff/gate interleaved slice -> rows [3072,11264) of the merged buffer.
__global__ void cast_ffg(const float* __restrict__ src, u16* __restrict__ dst) {
  const int i = blockIdx.x * 256 + threadIdx.x;  // over 8192*128
  const int l = blockIdx.y;
  const int r = i >> 7, cb = (i & 127) * 8;
  const int t16 = r >> 4, pos = r & 15;
  const int j = (t16 >> 1) * 16 + pos;
  const int srow = (t16 & 1) ? (3 * DD + FF + j) : (3 * DD + j);
  const float* s = src + ((size_t)l * FUSED + srow) * DD + cb;
  const float4 a = *(const float4*)s;
  const float4 b = *(const float4*)(s + 4);
  u16x8 o;
  o[0] = f2bf(a.x); o[1] = f2bf(a.y); o[2] = f2bf(a.z); o[3] = f2bf(a.w);
  o[4] = f2bf(b.x); o[5] = f2bf(b.y); o[6] = f2bf(b.z); o[7] = f2bf(b.w);
  *(u16x8*)(dst + ((size_t)l * FUSED + QKVW + r) * DD + cb) = o;
}

__global__ void cast_catw(const float* __restrict__ aw, const float* __restrict__ fw,
                          u16* __restrict__ dst) {
  const int i = blockIdx.x * 256 + threadIdx.x;  // over DD*640
  const int l = blockIdx.y;
  const int n = i / 640, cb = (i % 640) * 8;
  const float* s = (cb < DD) ? (aw + ((size_t)l * DD + n) * DD + cb)
                             : (fw + ((size_t)l * DD + n) * FF + (cb - DD));
  const float4 a = *(const float4*)s;
  const float4 b = *(const float4*)(s + 4);
  u16x8 o;
  o[0] = f2bf(a.x); o[1] = f2bf(a.y); o[2] = f2bf(a.z); o[3] = f2bf(a.w);
  o[4] = f2bf(b.x); o[5] = f2bf(b.y); o[6] = f2bf(b.z); o[7] = f2bf(b.w);
  *(u16x8*)(dst + ((size_t)l * DD + n) * CATW + cb) = o;
}

__global__ void add_bias(const float* __restrict__ a, const float* __restrict__ b,
                         float* __restrict__ o, int n) {
  const int i = blockIdx.x * 256 + threadIdx.x;
  if (i < n) o[i] = a[i] + b[i];
}

// ---------------------------------------------------------------------------
extern "C" void kernel_launch(void* const* d_in, const int* in_sizes, int n_in,
                              void* d_out, int out_size, void* d_ws, size_t ws_size,
                              hipStream_t stream) {
  const float* noisy   = (const float*)d_in[0];
  const float* condi   = (const float*)d_in[1];
  const float* prev    = (const float*)d_in[2];
  const float* infill  = (const float*)d_in[3];
  const float* amask   = (const float*)d_in[4];
  const float* times   = (const float*)d_in[5];
  const float* fourier = (const float*)d_in[6];
  const float* t1_w    = (const float*)d_in[7];
  const float* t1_b    = (const float*)d_in[8];
  const float* t2_w    = (const float*)d_in[9];
  const float* t2_b    = (const float*)d_in[10];
  const float* in_w    = (const float*)d_in[11];
  const float* in_b    = (const float*)d_in[12];
  const float* ln_w    = (const float*)d_in[13];
  const float* ln_b    = (const float*)d_in[14];
  const float* cond_w  = (const float*)d_in[15];
  const float* cond_b  = (const float*)d_in[16];
  const float* proj_w  = (const float*)d_in[17];
  const float* attn_w  = (const float*)d_in[18];
  const float* attn_b  = (const float*)d_in[19];
  const float* ff_w    = (const float*)d_in[20];
  const float* ff_b    = (const float*)d_in[21];
  const float* outln_w = (const float*)d_in[22];
  const float* outln_b = (const float*)d_in[23];
  const float* out_w   = (const float*)d_in[24];
  const float* out_b   = (const float*)d_in[25];
  const float* fin_w   = (const float*)d_in[26];
  const float* fin_b   = (const float*)d_in[27];
  float* outp = (float*)d_out;

  char* p = (char*)d_ws;
  auto alloc = [&](size_t bytes) -> char* {
    char* r = p;
    p += (bytes + 255) & ~(size_t)255;
    return r;
  };
  u16* in_w_h    = (u16*)alloc((size_t)DD * 2048 * 2);
  u16* qf_w_h    = (u16*)alloc((size_t)LL * FUSED * DD * 2);   // merged qkv+ffg weights
  u16* cat_w_h   = (u16*)alloc((size_t)LL * DD * CATW * 2);
  float* cat_b   = (float*)alloc((size_t)LL * DD * 4);
  u16* out_w_h   = (u16*)alloc((size_t)EE * DD * 2);
  float* te0 = (float*)alloc((size_t)BB * DD * 4);
  float* te1 = (float*)alloc((size_t)BB * DD * 4);
  float* te2 = (float*)alloc((size_t)BB * DD * 4);
  float* sb  = (float*)alloc((size_t)LL * BB * 2048 * 4);
  float* stab = (float*)alloc((size_t)SS * 32 * 4);
  float* ctab = (float*)alloc((size_t)SS * 32 * 4);
  u16* xb    = (u16*)alloc((size_t)NTOK * 2048 * 2);
  float* h   = (float*)alloc((size_t)NTOK * DD * 4);
  u16* units = (u16*)alloc((size_t)NTOK * DD * 2);
  u16* projq = (u16*)alloc((size_t)NTOK * QKVW * 2);
  u16* qrb   = (u16*)alloc((size_t)NTOK * DD * 2);
  u16* krb   = (u16*)alloc((size_t)NTOK * DD * 2);
  u16* vtb   = (u16*)alloc((size_t)NTOK * DD * 2);
  u16* acat  = (u16*)alloc((size_t)NTOK * CATW * 2);
  u16* hn    = (u16*)alloc((size_t)NTOK * DD * 2);
  float* ob  = (float*)alloc((size_t)NTOK * EE * 4);

  auto castN = [&](const float* src, u16* dst, size_t n) {
    const size_t n4 = n / 4;
    cast_bf16<<<dim3((unsigned)((n4 + 255) / 256)), dim3(256), 0, stream>>>(src, dst, n4);
  };
  castN(in_w, in_w_h, (size_t)DD * 2048);
  cast_q<<<dim3(QKVW * 128 / 256, LL), 256, 0, stream>>>(proj_w, qf_w_h);
  cast_ffg<<<dim3(8192 * 128 / 256, LL), 256, 0, stream>>>(proj_w, qf_w_h);
  cast_catw<<<dim3(DD * 640 / 256, LL), 256, 0, stream>>>(attn_w, ff_w, cat_w_h);
  add_bias<<<dim3(LL * DD / 256), 256, 0, stream>>>(attn_b, ff_b, cat_b, LL * DD);
  castN(out_w, out_w_h, (size_t)EE * DD);

  time_fourier<<<dim3(2, BB), 256, 0, stream>>>(times, fourier, te0);
  vec_gemm<0, 1><<<dim3(4, BB, 1), 256, 0, stream>>>(te0, t1_w, t1_b, te1, 1024, 1024);
  vec_gemm<0, 0><<<dim3(4, BB, 1), 256, 0, stream>>>(te1, t2_w, t2_b, te2, 1024, 1024);
  vec_gemm<1, 0><<<dim3(8, BB, LL), 256, 0, stream>>>(te2, cond_w, cond_b, sb, 2048, 1024);
  rope_tab<<<SS, 32, 0, stream>>>(stab, ctab);
  build_x<<<16384, 256, 0, stream>>>(noisy, condi, prev, infill, xb);
  gemm_bt<0, 0><<<dim3(DD / 128, NTOK / 128), 256, 0, stream>>>(xb, in_w_h, in_b, h, NTOK, DD, 2048);

  for (int l = 0; l < LL; l++) {
    ln_mod<<<NTOK, 256, 0, stream>>>(h, ln_w + (size_t)l * DD, ln_b + (size_t)l * DD,
                                     sb + (size_t)l * BB * 2048, units);
    gemm_qf256<<<dim3(FUSED / 256, NTOK / 256), 512, 0, stream>>>(
        units, qf_w_h + (size_t)l * FUSED * DD, projq, acat, NTOK, DD);
    rope_all<<<dim3(SS / 64, HH, BB), 256, 0, stream>>>(projq, stab, ctab, qrb, krb, vtb);
    attn_fwd<<<dim3(2048), 256, 0, stream>>>(qrb, krb, vtb, amask, acat);
    gemm_bt<1, 0><<<dim3(DD / 128, NTOK / 128), 256, 0, stream>>>(
        acat, cat_w_h + (size_t)l * DD * CATW, cat_b + (size_t)l * DD, h, NTOK, DD, CATW);
  }

  ln_mod<<<NTOK, 256, 0, stream>>>(h, outln_w, outln_b, nullptr, hn);
  gemm_bt<0, 0><<<dim3(EE / 128, NTOK / 128), 256, 0, stream>>>(hn, out_w_h, out_b, ob, NTOK, EE, DD);
  ln_fin<<<NTOK, 128, 0, stream>>>(ob, fin_w, fin_b, outp);
}

// Round 13
// 4494.772 us; speedup vs baseline: 1.0347x; 1.0347x over previous
//
#include <hip/hip_runtime.h>
#include <hip/hip_bf16.h>
#include <cstddef>
#include <cstdint>

// Problem constants
#define BB 8
#define SS 1024
#define EE 512
#define DD 1024
#define LL 8
#define HH 16
#define HD 64
#define ROT 32
#define FF 4096
#define FUSED 11264   // 3*D + 2*FF
#define NTOK 8192     // B*S
#define QKVW 3072     // width of qkv projection buffer
#define CATW 5120     // attn-out (1024) + gated-ff (4096) concat width

using u16 = unsigned short;
typedef __attribute__((ext_vector_type(8))) __bf16 bf16x8;
typedef __attribute__((ext_vector_type(4))) float f32x4;
typedef __attribute__((ext_vector_type(4))) unsigned short u16x4;
typedef __attribute__((ext_vector_type(8))) unsigned short u16x8;

typedef const __attribute__((address_space(1))) void gas_t;
typedef __attribute__((address_space(3))) void las_t;

#define VMCNT8 asm volatile("s_waitcnt vmcnt(8)" ::: "memory")
#define VMCNT0 asm volatile("s_waitcnt vmcnt(0)" ::: "memory")

__device__ __forceinline__ void gld16(const void* g, void* l) {
  __builtin_amdgcn_global_load_lds((gas_t*)g, (las_t*)l, 16, 0, 0);
}

__device__ __forceinline__ float bf2f(u16 u) {
  union { unsigned int i; float f; } v; v.i = ((unsigned int)u) << 16; return v.f;
}
__device__ __forceinline__ u16 f2bf(float f) {
  union { float f; unsigned int i; } v; v.f = f;
  unsigned int u = v.i;
  unsigned int r = u + 0x7FFFu + ((u >> 16) & 1u);
  return (u16)(r >> 16);
}
__device__ __forceinline__ float gelu_f(float x) {
  return x * 0.5f * (1.0f + erff(x / 1.41421f));
}
__device__ __forceinline__ float silu_f(float x) {
  return x / (1.0f + __expf(-x));
}

// ---------------------------------------------------------------------------
// Generic bf16 B^T GEMM: C[M,N] (+)= A[M,K] * W[N,K]^T (+ bias[N])
// 128x128 tile, BK=64, 4 waves (2x2). Counted-vmcnt two-barrier K-loop.
// ACCUM=1: bf16 read-modify-write (residual stream h is bf16).
// ---------------------------------------------------------------------------
template <int ACCUM, int OUTBF16>
__global__ __launch_bounds__(256, 2) void gemm_bt(
    const u16* __restrict__ A, const u16* __restrict__ W,
    const float* __restrict__ bias, void* __restrict__ Cp,
    int M, int N, int K) {
  __shared__ __align__(16) u16 As[2][128 * 64];
  __shared__ __align__(16) u16 Bs[2][128 * 64];
  const int tid = threadIdx.x;
  const int w = tid >> 6, lane = tid & 63;
  const int m0 = blockIdx.y * 128, n0 = blockIdx.x * 128;
  const int wm = w >> 1, wn = w & 1;

  f32x4 acc[4][4] = {};

  auto stage = [&](int buf, int k0) {
#pragma unroll
    for (int i = 0; i < 4; i++) {
      const int c = w + i * 4;                 // 1KB chunk id, 0..15
      const int r = c * 8 + (lane >> 3);       // tile row (128B rows)
      const int colb = ((lane & 7) << 4) ^ ((r & 7) << 4);  // pre-swizzled src col
      gld16(A + (size_t)(m0 + r) * K + k0 + (colb >> 1), &As[buf][c * 512]);
      gld16(W + (size_t)(n0 + r) * K + k0 + (colb >> 1), &Bs[buf][c * 512]);
    }
  };

  const int nt = K >> 6;
  stage(0, 0);

  for (int t = 0; t < nt; t++) {
    const int cur = t & 1;
    if (t + 1 < nt) {
      stage(cur ^ 1, (t + 1) << 6);
      VMCNT8;
    } else {
      VMCNT0;
    }
    __builtin_amdgcn_s_barrier();   // buf[cur] published (all waves)

    bf16x8 av0[4], bv0[4], av1[4], bv1[4];
#pragma unroll
    for (int m = 0; m < 4; m++) {
      const int row = wm * 64 + m * 16 + (lane & 15);
      const int sw = (row & 7) << 4;
      av0[m] = *(const bf16x8*)((const char*)As[cur] + row * 128 + ((((lane >> 4) << 4)) ^ sw));
      av1[m] = *(const bf16x8*)((const char*)As[cur] + row * 128 + ((64 + ((lane >> 4) << 4)) ^ sw));
    }
#pragma unroll
    for (int n = 0; n < 4; n++) {
      const int row = wn * 64 + n * 16 + (lane & 15);
      const int sw = (row & 7) << 4;
      bv0[n] = *(const bf16x8*)((const char*)Bs[cur] + row * 128 + ((((lane >> 4) << 4)) ^ sw));
      bv1[n] = *(const bf16x8*)((const char*)Bs[cur] + row * 128 + ((64 + ((lane >> 4) << 4)) ^ sw));
    }
    __builtin_amdgcn_s_setprio(1);
#pragma unroll
    for (int m = 0; m < 4; m++)
#pragma unroll
      for (int n = 0; n < 4; n++)
        acc[m][n] = __builtin_amdgcn_mfma_f32_16x16x32_bf16(av0[m], bv0[n], acc[m][n], 0, 0, 0);
#pragma unroll
    for (int m = 0; m < 4; m++)
#pragma unroll
      for (int n = 0; n < 4; n++)
        acc[m][n] = __builtin_amdgcn_mfma_f32_16x16x32_bf16(av1[m], bv1[n], acc[m][n], 0, 0, 0);
    __builtin_amdgcn_s_setprio(0);
    __builtin_amdgcn_s_barrier();   // buf[cur] free for overwrite next iter
  }

  const int rowb0 = m0 + wm * 64 + ((lane >> 4) << 2);
  const int colb0 = n0 + wn * 64 + (lane & 15);
#pragma unroll
  for (int n = 0; n < 4; n++) {
    const int col = colb0 + n * 16;
    const float bn = bias ? bias[col] : 0.0f;
#pragma unroll
    for (int m = 0; m < 4; m++) {
#pragma unroll
      for (int r = 0; r < 4; r++) {
        const size_t idx = (size_t)(rowb0 + m * 16 + r) * N + col;
        const float v = acc[m][n][r] + bn;
        if (ACCUM) {
          u16* c = (u16*)Cp;
          c[idx] = f2bf(bf2f(c[idx]) + v);   // bf16 residual RMW
        } else if (OUTBF16) {
          ((u16*)Cp)[idx] = f2bf(v);
        } else {
          ((float*)Cp)[idx] = v;
        }
      }
    }
  }
}

// ---------------------------------------------------------------------------
// Merged qkv+ffg 256x256-tile bf16 B^T GEMM (8 waves 2Mx4N, BK=64, 128KB LDS
// dbuf, counted-vmcnt two-barrier pipeline). Weight rows [0,3072) = qkv;
// rows [3072,11264) = ff/gate interleaved per 16-col group. Epilogue branches
// on wave-uniform n0: qkv -> projq; gated -> acat cols [1024,5120).
// ---------------------------------------------------------------------------
__global__ __launch_bounds__(512, 2) void gemm_qf256(
    const u16* __restrict__ A, const u16* __restrict__ W,
    u16* __restrict__ projq, u16* __restrict__ acat, int M, int K) {
  __shared__ __align__(16) u16 As[2][256 * 64];   // 64 KB
  __shared__ __align__(16) u16 Bs[2][256 * 64];   // 64 KB
  const int tid = threadIdx.x;
  const int w = tid >> 6, lane = tid & 63;
  const int m0 = blockIdx.y * 256, n0 = blockIdx.x * 256;
  const int wm = w >> 2, wn = w & 3;   // 2 x 4 wave grid

  f32x4 acc[8][4] = {};

  auto stage = [&](int buf, int k0) {
#pragma unroll
    for (int i = 0; i < 4; i++) {
      const int c = w + i * 8;                 // 1KB chunk id, 0..31
      const int r = c * 8 + (lane >> 3);       // tile row 0..255 (128B rows)
      const int colb = ((lane & 7) << 4) ^ ((r & 7) << 4);
      gld16(A + (size_t)(m0 + r) * K + k0 + (colb >> 1), &As[buf][c * 512]);
      gld16(W + (size_t)(n0 + r) * K + k0 + (colb >> 1), &Bs[buf][c * 512]);
    }
  };

  const int nt = K >> 6;
  stage(0, 0);

  for (int t = 0; t < nt; t++) {
    const int cur = t & 1;
    if (t + 1 < nt) {
      stage(cur ^ 1, (t + 1) << 6);
      VMCNT8;
    } else {
      VMCNT0;
    }
    __builtin_amdgcn_s_barrier();

    // ks=0
    {
      bf16x8 av0[8], bv0[4];
#pragma unroll
      for (int m = 0; m < 8; m++) {
        const int row = wm * 128 + m * 16 + (lane & 15);
        const int cb = (((lane >> 4) << 4)) ^ ((row & 7) << 4);
        av0[m] = *(const bf16x8*)((const char*)As[cur] + row * 128 + cb);
      }
#pragma unroll
      for (int n = 0; n < 4; n++) {
        const int row = wn * 64 + n * 16 + (lane & 15);
        const int cb = (((lane >> 4) << 4)) ^ ((row & 7) << 4);
        bv0[n] = *(const bf16x8*)((const char*)Bs[cur] + row * 128 + cb);
      }
      __builtin_amdgcn_s_setprio(1);
#pragma unroll
      for (int m = 0; m < 8; m++)
#pragma unroll
        for (int n = 0; n < 4; n++)
          acc[m][n] = __builtin_amdgcn_mfma_f32_16x16x32_bf16(av0[m], bv0[n], acc[m][n], 0, 0, 0);
      __builtin_amdgcn_s_setprio(0);
    }
    // ks=1
    {
      bf16x8 av1[8], bv1[4];
#pragma unroll
      for (int m = 0; m < 8; m++) {
        const int row = wm * 128 + m * 16 + (lane & 15);
        const int cb = (64 + ((lane >> 4) << 4)) ^ ((row & 7) << 4);
        av1[m] = *(const bf16x8*)((const char*)As[cur] + row * 128 + cb);
      }
#pragma unroll
      for (int n = 0; n < 4; n++) {
        const int row = wn * 64 + n * 16 + (lane & 15);
        const int cb = (64 + ((lane >> 4) << 4)) ^ ((row & 7) << 4);
        bv1[n] = *(const bf16x8*)((const char*)Bs[cur] + row * 128 + cb);
      }
      __builtin_amdgcn_s_setprio(1);
#pragma unroll
      for (int m = 0; m < 8; m++)
#pragma unroll
        for (int n = 0; n < 4; n++)
          acc[m][n] = __builtin_amdgcn_mfma_f32_16x16x32_bf16(av1[m], bv1[n], acc[m][n], 0, 0, 0);
      __builtin_amdgcn_s_setprio(0);
    }
    __builtin_amdgcn_s_barrier();
  }

  const int rowb0 = m0 + wm * 128 + ((lane >> 4) << 2);
  if (n0 >= QKVW) {
    const int ocol0 = DD + ((n0 - QKVW) >> 1);
#pragma unroll
    for (int n = 0; n < 4; n += 2) {
      const int outcol = ocol0 + wn * 32 + ((n >> 1) << 4) + (lane & 15);
#pragma unroll
      for (int m = 0; m < 8; m++)
#pragma unroll
        for (int r = 0; r < 4; r++) {
          const float fv = acc[m][n][r];
          const float gv = acc[m][n + 1][r];
          acat[(size_t)(rowb0 + m * 16 + r) * CATW + outcol] = f2bf(fv * gelu_f(gv));
        }
    }
  } else {
    const int colb0 = n0 + wn * 64 + (lane & 15);
#pragma unroll
    for (int n = 0; n < 4; n++) {
      const int col = colb0 + n * 16;
#pragma unroll
      for (int m = 0; m < 8; m++)
#pragma unroll
        for (int r = 0; r < 4; r++)
          projq[(size_t)(rowb0 + m * 16 + r) * QKVW + col] = f2bf(acc[m][n][r]);
    }
  }
}

// ---------------------------------------------------------------------------
// Flash attention: swapped QK^T, tree row-max, T13 defer-max, T12 cvt_pk.
// Output into acat cols [0,1024), row stride CATW.
// ---------------------------------------------------------------------------
__global__ __launch_bounds__(256, 2) void attn_fwd(
    const u16* __restrict__ qr, const u16* __restrict__ kr,
    const u16* __restrict__ vt, const float* __restrict__ mask,
    u16* __restrict__ acat) {
  __shared__ __align__(16) u16 Ks[2][128 * 64];   // [key][dim], swizzled
  __shared__ __align__(16) u16 Vs[2][64 * 128];   // [d][key], swizzled
  __shared__ __align__(16) u16 Ps[4][16 * 128];   // per-wave P [q][k], XOR-swizzled
  const int tid = threadIdx.x, w = tid >> 6, lane = tid & 63;
  const int g = blockIdx.x;
  const int j = g >> 3;
  const int bh = (g & 7) + ((j >> 4) << 3);
  const int qx = j & 15;
  const int b = bh >> 4;
  const int q0 = qx * 64 + w * 16;
  const u16* Qb = qr + (size_t)bh * SS * HD;
  const u16* Kb = kr + (size_t)bh * SS * HD;
  const u16* Vb = vt + (size_t)bh * HD * SS;
  const float* mb = mask + (size_t)b * SS;
  const int lq = lane & 15, lg = lane >> 4;

  bf16x8 qf0, qf1;
  {
    const int qrow = q0 + lq;
    const u16* qp = Qb + (size_t)qrow * HD + (lg << 3);
    qf0 = *(const bf16x8*)qp;
    qf1 = *(const bf16x8*)(qp + 32);
  }

  float mrun = -1e30f, srun = 0.0f;   // running stats for q-row = lq
  f32x4 acc[4] = {};

  u16* pw = &Ps[w][0];

  auto stage = [&](int buf, int kv0) {
#pragma unroll
    for (int i = 0; i < 4; i++) {
      const int c = w + i * 4;
      {
        const int r = c * 8 + (lane >> 3);
        const int colb = ((lane & 7) << 4) ^ ((r & 7) << 4);
        gld16(Kb + (size_t)(kv0 + r) * HD + (colb >> 1), &Ks[buf][c * 512]);
      }
      {
        const int d = c * 4 + lg;
        const int colb = (lq << 4) ^ ((d & 7) << 4);
        gld16(Vb + (size_t)d * SS + kv0 + (colb >> 1), &Vs[buf][c * 512]);
      }
    }
  };

  stage(0, 0);
  __syncthreads();

  for (int t = 0; t < 8; t++) {
    const int cur = t & 1;
    const int kv0 = t * 128;
    if (t < 7) stage(cur ^ 1, kv0 + 128);

    // swapped QK^T: p[blk][r] = P[key = blk*16 + lg*4 + r][q = lq]
    f32x4 p[8];
    __builtin_amdgcn_s_setprio(1);
#pragma unroll
    for (int blk = 0; blk < 8; blk++) {
      const int row = blk * 16 + lq;
      const int swz = (row & 7) << 4;
      const bf16x8 k0v = *(const bf16x8*)((const char*)Ks[cur] + row * 128 + (((lg << 4)) ^ swz));
      const bf16x8 k1v = *(const bf16x8*)((const char*)Ks[cur] + row * 128 + ((64 + (lg << 4)) ^ swz));
      f32x4 z = {};
      p[blk] = __builtin_amdgcn_mfma_f32_16x16x32_bf16(k0v, qf0, z, 0, 0, 0);
      p[blk] = __builtin_amdgcn_mfma_f32_16x16x32_bf16(k1v, qf1, p[blk], 0, 0, 0);
    }
    __builtin_amdgcn_s_setprio(0);

#pragma unroll
    for (int blk = 0; blk < 8; blk++) {
      const float4 m4 = *(const float4*)(mb + kv0 + blk * 16 + (lg << 2));
      p[blk][0] = p[blk][0] * (1.0f / 64.0f) + m4.x;
      p[blk][1] = p[blk][1] * (1.0f / 64.0f) + m4.y;
      p[blk][2] = p[blk][2] * (1.0f / 64.0f) + m4.z;
      p[blk][3] = p[blk][3] * (1.0f / 64.0f) + m4.w;
    }

    // tree row-max (shallow dependency chains)
    float mr[8];
#pragma unroll
    for (int blk = 0; blk < 8; blk++)
      mr[blk] = fmaxf(fmaxf(p[blk][0], p[blk][1]), fmaxf(p[blk][2], p[blk][3]));
    float mrow = fmaxf(fmaxf(fmaxf(mr[0], mr[1]), fmaxf(mr[2], mr[3])),
                       fmaxf(fmaxf(mr[4], mr[5]), fmaxf(mr[6], mr[7])));
    mrow = fmaxf(mrow, __shfl_xor(mrow, 16));
    mrow = fmaxf(mrow, __shfl_xor(mrow, 32));

    if (__any(mrow > mrun)) {       // T13 defer-max (exact at THR=0)
      const float mn = fmaxf(mrun, mrow);
      const float facq = __expf(mrun - mn);
      mrun = mn;
      srun *= facq;
      float fac[4];
#pragma unroll
      for (int r = 0; r < 4; r++)
        fac[r] = __shfl(facq, (lane & 48) | ((lg << 2) + r));
#pragma unroll
      for (int dblk = 0; dblk < 4; dblk++)
#pragma unroll
        for (int r = 0; r < 4; r++) acc[dblk][r] *= fac[r];
    }

    // exp + 4-way parallel sum + cvt_pk bf16 pack (T12)
    float rs0 = 0.0f, rs1 = 0.0f, rs2 = 0.0f, rs3 = 0.0f;
#pragma unroll
    for (int blk = 0; blk < 8; blk++) {
      const float e0 = __expf(p[blk][0] - mrun);
      const float e1 = __expf(p[blk][1] - mrun);
      const float e2 = __expf(p[blk][2] - mrun);
      const float e3 = __expf(p[blk][3] - mrun);
      rs0 += e0; rs1 += e1; rs2 += e2; rs3 += e3;
      unsigned int r01, r23;
      asm("v_cvt_pk_bf16_f32 %0, %1, %2" : "=v"(r01) : "v"(e0), "v"(e1));
      asm("v_cvt_pk_bf16_f32 %0, %1, %2" : "=v"(r23) : "v"(e2), "v"(e3));
      uint2 pk; pk.x = r01; pk.y = r23;
      *(uint2*)(pw + ((lq * 128 + blk * 16 + (lg << 2)) ^ ((lq & 7) << 3))) = pk;
    }
    float rs = (rs0 + rs1) + (rs2 + rs3);
    rs += __shfl_xor(rs, 16);
    rs += __shfl_xor(rs, 32);
    srun += rs;

    bf16x8 pa[4];
#pragma unroll
    for (int ks = 0; ks < 4; ks++)
      pa[ks] = *(const bf16x8*)(pw + ((lq * 128 + ks * 32 + (lg << 3)) ^ ((lq & 7) << 3)));

    __builtin_amdgcn_s_setprio(1);
#pragma unroll
    for (int dblk = 0; dblk < 4; dblk++) {
      const int drow = dblk * 16 + lq;
      const int swz = (drow & 7) << 4;
#pragma unroll
      for (int ks = 0; ks < 4; ks++) {
        const bf16x8 vv = *(const bf16x8*)((const char*)Vs[cur] + drow * 256 + ((ks * 64 + (lg << 4)) ^ swz));
        acc[dblk] = __builtin_amdgcn_mfma_f32_16x16x32_bf16(pa[ks], vv, acc[dblk], 0, 0, 0);
      }
    }
    __builtin_amdgcn_s_setprio(0);

    __syncthreads();
  }

  float sden[4];
#pragma unroll
  for (int r = 0; r < 4; r++)
    sden[r] = __shfl(srun, (lane & 48) | ((lg << 2) + r));
#pragma unroll
  for (int dblk = 0; dblk < 4; dblk++)
#pragma unroll
    for (int r = 0; r < 4; r++) {
      const int sq = q0 + (lg << 2) + r;
      const int d = dblk * 16 + lq;
      acat[((size_t)b * SS + sq) * CATW + (bh & 15) * HD + d] = f2bf(acc[dblk][r] / sden[r]);
    }
}

// ---------------------------------------------------------------------------
// LayerNorm (+ optional AdaLN modulation) over D=1024, one block per row.
// Input h is bf16 (residual stream).
// ---------------------------------------------------------------------------
__global__ __launch_bounds__(256) void ln_mod(
    const u16* __restrict__ x, const float* __restrict__ lw,
    const float* __restrict__ lb, const float* __restrict__ sb,
    u16* __restrict__ out) {
  const int row = blockIdx.x, tid = threadIdx.x;
  const u16x4 hv = *(const u16x4*)(x + (size_t)row * DD + tid * 4);
  float vv[4] = {bf2f(hv[0]), bf2f(hv[1]), bf2f(hv[2]), bf2f(hv[3])};
  float s = vv[0] + vv[1] + vv[2] + vv[3];
  float q = vv[0] * vv[0] + vv[1] * vv[1] + vv[2] * vv[2] + vv[3] * vv[3];
  for (int off = 1; off < 64; off <<= 1) {
    s += __shfl_xor(s, off);
    q += __shfl_xor(q, off);
  }
  __shared__ float red[8];
  const int w = tid >> 6, lane = tid & 63;
  if (lane == 0) { red[w] = s; red[4 + w] = q; }
  __syncthreads();
  s = red[0] + red[1] + red[2] + red[3];
  q = red[4] + red[5] + red[6] + red[7];
  const float mu = s * (1.0f / DD);
  const float inv = rsqrtf(q * (1.0f / DD) - mu * mu + 1e-5f);
  const int b = row >> 10;
  u16x4 o;
#pragma unroll
  for (int j = 0; j < 4; j++) {
    const int d = tid * 4 + j;
    float g = (vv[j] - mu) * inv * lw[d] + lb[d];
    if (sb) g = (1.0f + sb[(size_t)b * 2048 + d]) * g + sb[(size_t)b * 2048 + DD + d];
    o[j] = f2bf(g);
  }
  *(u16x4*)(out + (size_t)row * DD + tid * 4) = o;
}

// Final LayerNorm over E=512, f32 out. One block (128 threads) per row.
__global__ __launch_bounds__(128) void ln_fin(
    const float* __restrict__ x, const float* __restrict__ w_,
    const float* __restrict__ b_, float* __restrict__ out) {
  const int row = blockIdx.x, tid = threadIdx.x;
  const float4 v = ((const float4*)(x + (size_t)row * EE))[tid];
  float vv[4] = {v.x, v.y, v.z, v.w};
  float s = vv[0] + vv[1] + vv[2] + vv[3];
  float q = vv[0] * vv[0] + vv[1] * vv[1] + vv[2] * vv[2] + vv[3] * vv[3];
  for (int off = 1; off < 64; off <<= 1) {
    s += __shfl_xor(s, off);
    q += __shfl_xor(q, off);
  }
  __shared__ float red[4];
  const int w = tid >> 6, lane = tid & 63;
  if (lane == 0) { red[w] = s; red[2 + w] = q; }
  __syncthreads();
  s = red[0] + red[1];
  q = red[2] + red[3];
  const float mu = s * (1.0f / EE);
  const float inv = rsqrtf(q * (1.0f / EE) - mu * mu + 1e-5f);
  float4 o;
  o.x = (vv[0] - mu) * inv * w_[tid * 4 + 0] + b_[tid * 4 + 0];
  o.y = (vv[1] - mu) * inv * w_[tid * 4 + 1] + b_[tid * 4 + 1];
  o.z = (vv[2] - mu) * inv * w_[tid * 4 + 2] + b_[tid * 4 + 2];
  o.w = (vv[3] - mu) * inv * w_[tid * 4 + 3] + b_[tid * 4 + 3];
  ((float4*)(out + (size_t)row * EE))[tid] = o;
}

template <int IA, int OA>
__global__ __launch_bounds__(256) void vec_gemm(
    const float* __restrict__ in, const float* __restrict__ W,
    const float* __restrict__ bias, float* __restrict__ out, int N, int K) {
  const int n = blockIdx.x * 256 + threadIdx.x;
  const int b = blockIdx.y, l = blockIdx.z;
  const float* ir = in + (size_t)b * K;
  const float* wr = W + ((size_t)l * N + n) * K;
  float s = bias[(size_t)l * N + n];
  for (int k = 0; k < K; k += 4) {
    float4 a = *(const float4*)(ir + k);
    const float4 ww = *(const float4*)(wr + k);
    if (IA) { a.x = silu_f(a.x); a.y = silu_f(a.y); a.z = silu_f(a.z); a.w = silu_f(a.w); }
    s += a.x * ww.x + a.y * ww.y + a.z * ww.z + a.w * ww.w;
  }
  if (OA) s = gelu_f(s);
  out[((size_t)l * gridDim.y + b) * N + n] = s;
}

__global__ void time_fourier(const float* __restrict__ times,
                             const float* __restrict__ fw, float* __restrict__ te0) {
  const int j = blockIdx.x * 256 + threadIdx.x;
  const int b = blockIdx.y;
  const float f = 6.28318530717958647692f * times[b] * fw[j];
  te0[(size_t)b * DD + j] = cosf(f);
  te0[(size_t)b * DD + 512 + j] = sinf(f);
}

__global__ void rope_tab(float* __restrict__ st, float* __restrict__ ct) {
  const int s = blockIdx.x;
  const int j = threadIdx.x;
  const int i = j & 15;
  const float inv = powf(10000.0f, -(float)i * (1.0f / 16.0f));
  const float f = (float)s * inv;
  st[s * 32 + j] = bf2f(f2bf(sinf(f)));
  ct[s * 32 + j] = bf2f(f2bf(cosf(f)));
}

__global__ void build_x(const float* __restrict__ a, const float* __restrict__ b,
                        const float* __restrict__ c, const float* __restrict__ m,
                        u16* __restrict__ x) {
  const size_t i4 = ((size_t)blockIdx.x * 256 + threadIdx.x) * 4;
  if (i4 >= (size_t)NTOK * 2048) return;
  const size_t tok = i4 >> 11;
  const int e = (int)(i4 & 2047);
  float4 v;
  if (e < 512)       v = *(const float4*)(a + tok * 512 + e);
  else if (e < 1024) v = *(const float4*)(b + tok * 512 + (e - 512));
  else if (e < 1536) v = *(const float4*)(c + tok * 512 + (e - 1024));
  else { const float mm = m[tok]; v = make_float4(mm, mm, mm, mm); }
  u16x4 o;
  o[0] = f2bf(v.x); o[1] = f2bf(v.y); o[2] = f2bf(v.z); o[3] = f2bf(v.w);
  *(u16x4*)(x + i4) = o;
}

// ---------------------------------------------------------------------------
// Fused RoPE(q,k) + head-split + V-transpose. grid (S/64, H, B), 256 threads.
// ---------------------------------------------------------------------------
__global__ __launch_bounds__(256) void rope_all(
    const u16* __restrict__ proj, const float* __restrict__ st,
    const float* __restrict__ ct, u16* __restrict__ q, u16* __restrict__ k,
    u16* __restrict__ v) {
  __shared__ u16 tile[4 * 1160];
  const int tid = threadIdx.x;
  const int s0 = blockIdx.x * 64, h = blockIdx.y, b = blockIdx.z;
  const int sl = tid >> 2, c = tid & 3;
  const int s = s0 + sl;
  const u16* pr = proj + (size_t)(b * SS + s) * QKVW + h * 64;

  {
    const u16x8 a0 = *(const u16x8*)(pr + 2 * DD + c * 16);
    const u16x8 a1 = *(const u16x8*)(pr + 2 * DD + c * 16 + 8);
    u16* trow = &tile[(sl >> 4) * 1160 + (sl & 15) * 72];
    *(u16x8*)&trow[c * 16] = a0;
    *(u16x8*)&trow[c * 16 + 8] = a1;
  }

  {
    const int d0 = c * 16;
    u16 qv[16], kv[16], qo[16], ko[16];
    *(u16x8*)&qv[0] = *(const u16x8*)(pr + d0);
    *(u16x8*)&qv[8] = *(const u16x8*)(pr + d0 + 8);
    *(u16x8*)&kv[0] = *(const u16x8*)(pr + DD + d0);
    *(u16x8*)&kv[8] = *(const u16x8*)(pr + DD + d0 + 8);
    if (c < 2) {
      const int dp = (c ^ 1) * 16;
      u16 qp[16], kp[16];
      *(u16x8*)&qp[0] = *(const u16x8*)(pr + dp);
      *(u16x8*)&qp[8] = *(const u16x8*)(pr + dp + 8);
      *(u16x8*)&kp[0] = *(const u16x8*)(pr + DD + dp);
      *(u16x8*)&kp[8] = *(const u16x8*)(pr + DD + dp + 8);
      const float sg = (c == 0) ? -1.0f : 1.0f;
#pragma unroll
      for (int j = 0; j < 16; j++) {
        const int d = d0 + j;
        const float cs = ct[s * 32 + d], sn = st[s * 32 + d];
        qo[j] = f2bf(bf2f(qv[j]) * cs + sg * bf2f(qp[j]) * sn);
        ko[j] = f2bf(bf2f(kv[j]) * cs + sg * bf2f(kp[j]) * sn);
      }
    } else {
#pragma unroll
      for (int j = 0; j < 16; j++) { qo[j] = qv[j]; ko[j] = kv[j]; }
    }
    u16* qd = q + ((size_t)(b * HH + h) * SS + s) * HD + d0;
    u16* kd = k + ((size_t)(b * HH + h) * SS + s) * HD + d0;
    *(u16x8*)qd = *(u16x8*)&qo[0];
    *(u16x8*)(qd + 8) = *(u16x8*)&qo[8];
    *(u16x8*)kd = *(u16x8*)&ko[0];
    *(u16x8*)(kd + 8) = *(u16x8*)&ko[8];
  }

  __syncthreads();

  {
    const int dl = tid >> 2, gq = tid & 3;   // qs = gq*16
    const u16* tg = &tile[gq * 1160];
    u16x8 o0, o1;
#pragma unroll
    for (int j = 0; j < 8; j++) o0[j] = tg[j * 72 + dl];
#pragma unroll
    for (int j = 0; j < 8; j++) o1[j] = tg[(8 + j) * 72 + dl];
    u16* dst = v + ((size_t)(b * HH + h) * HD + dl) * SS + s0 + gq * 16;
    *(u16x8*)dst = o0;
    *(u16x8*)(dst + 8) = o1;
  }
}

__global__ void cast_bf16(const float* __restrict__ in, u16* __restrict__ out, size_t n4) {
  const size_t i = (size_t)blockIdx.x * 256 + threadIdx.x;
  if (i >= n4) return;
  const float4 v = ((const float4*)in)[i];
  u16x4 o;
  o[0] = f2bf(v.x); o[1] = f2bf(v.y); o[2] = f2bf(v.z); o[3] = f2bf(v.w);
  ((u16x4*)out)[i] = o;
}

// qkv slice of proj_w -> rows [0,3072) of the merged [11264][1024] buffer.
__global__ void cast_q(const float* __restrict__ src, u16* __restrict__ dst) {
  const int i = blockIdx.x * 256 + threadIdx.x;  // over 3072*128
  const int l = blockIdx.y;
  const int r = i >> 7, cb = (i & 127) * 8;
  const float* s = src + ((size_t)l * FUSED + r) * DD + cb;
  const float4 a = *(const float4*)s;
  const float4 b = *(const float4*)(s + 4);
  u16x8 o;
  o[0] = f2bf(a.x); o[1] = f2bf(a.y); o[2] = f2bf(a.z); o[3] = f2bf(a.w);
  o[4] = f2bf(b.x); o[5] = f2bf(b.y); o[6] = f2bf(b.z); o[7] = f2bf(b.w);
  *(u16x8*)(dst + ((size_t)l * FUSED + r) * DD + cb) = o;
}

// ff/gate interleaved slice -> rows [3072,11264) of the merged buffer.
__global__ void cast_ffg(const float* __restrict__ src, u16* __restrict__ dst) {
  const int i = blockIdx.x * 256 + threadIdx.x;  // over 8192*128
  const int l = blockIdx.y;
  const int r = i >> 7, cb = (i & 127) * 8;
  const int t16 = r >> 4, pos = r & 15;
  const int j = (t16 >> 1) * 16 + pos;
  const int srow = (t16 & 1) ? (3 * DD + FF + j) : (3 * DD + j);
  const float* s = src + ((size_t)l * FUSED + srow) * DD + cb;
  const float4 a = *(const float4*)s;
  const float4 b = *(const float4*)(s + 4);
  u16x8 o;
  o[0] = f2bf(a.x); o[1] = f2bf(a.y); o[2] = f2bf(a.z); o[3] = f2bf(a.w);
  o[4] = f2bf(b.x); o[5] = f2bf(b.y); o[6] = f2bf(b.z); o[7] = f2bf(b.w);
  *(u16x8*)(dst + ((size_t)l * FUSED + QKVW + r) * DD + cb) = o;
}

__global__ void cast_catw(const float* __restrict__ aw, const float* __restrict__ fw,
                          u16* __restrict__ dst) {
  const int i = blockIdx.x * 256 + threadIdx.x;  // over DD*640
  const int l = blockIdx.y;
  const int n = i / 640, cb = (i % 640) * 8;
  const float* s = (cb < DD) ? (aw + ((size_t)l * DD + n) * DD + cb)
                             : (fw + ((size_t)l * DD + n) * FF + (cb - DD));
  const float4 a = *(const float4*)s;
  const float4 b = *(const float4*)(s + 4);
  u16x8 o;
  o[0] = f2bf(a.x); o[1] = f2bf(a.y); o[2] = f2bf(a.z); o[3] = f2bf(a.w);
  o[4] = f2bf(b.x); o[5] = f2bf(b.y); o[6] = f2bf(b.z); o[7] = f2bf(b.w);
  *(u16x8*)(dst + ((size_t)l * DD + n) * CATW + cb) = o;
}

__global__ void add_bias(const float* __restrict__ a, const float* __restrict__ b,
                         float* __restrict__ o, int n) {
  const int i = blockIdx.x * 256 + threadIdx.x;
  if (i < n) o[i] = a[i] + b[i];
}

// ---------------------------------------------------------------------------
extern "C" void kernel_launch(void* const* d_in, const int* in_sizes, int n_in,
                              void* d_out, int out_size, void* d_ws, size_t ws_size,
                              hipStream_t stream) {
  const float* noisy   = (const float*)d_in[0];
  const float* condi   = (const float*)d_in[1];
  const float* prev    = (const float*)d_in[2];
  const float* infill  = (const float*)d_in[3];
  const float* amask   = (const float*)d_in[4];
  const float* times   = (const float*)d_in[5];
  const float* fourier = (const float*)d_in[6];
  const float* t1_w    = (const float*)d_in[7];
  const float* t1_b    = (const float*)d_in[8];
  const float* t2_w    = (const float*)d_in[9];
  const float* t2_b    = (const float*)d_in[10];
  const float* in_w    = (const float*)d_in[11];
  const float* in_b    = (const float*)d_in[12];
  const float* ln_w    = (const float*)d_in[13];
  const float* ln_b    = (const float*)d_in[14];
  const float* cond_w  = (const float*)d_in[15];
  const float* cond_b  = (const float*)d_in[16];
  const float* proj_w  = (const float*)d_in[17];
  const float* attn_w  = (const float*)d_in[18];
  const float* attn_b  = (const float*)d_in[19];
  const float* ff_w    = (const float*)d_in[20];
  const float* ff_b    = (const float*)d_in[21];
  const float* outln_w = (const float*)d_in[22];
  const float* outln_b = (const float*)d_in[23];
  const float* out_w   = (const float*)d_in[24];
  const float* out_b   = (const float*)d_in[25];
  const float* fin_w   = (const float*)d_in[26];
  const float* fin_b   = (const float*)d_in[27];
  float* outp = (float*)d_out;

  char* p = (char*)d_ws;
  auto alloc = [&](size_t bytes) -> char* {
    char* r = p;
    p += (bytes + 255) & ~(size_t)255;
    return r;
  };
  u16* in_w_h    = (u16*)alloc((size_t)DD * 2048 * 2);
  u16* qf_w_h    = (u16*)alloc((size_t)LL * FUSED * DD * 2);   // merged qkv+ffg weights
  u16* cat_w_h   = (u16*)alloc((size_t)LL * DD * CATW * 2);
  float* cat_b   = (float*)alloc((size_t)LL * DD * 4);
  u16* out_w_h   = (u16*)alloc((size_t)EE * DD * 2);
  float* te0 = (float*)alloc((size_t)BB * DD * 4);
  float* te1 = (float*)alloc((size_t)BB * DD * 4);
  float* te2 = (float*)alloc((size_t)BB * DD * 4);
  float* sb  = (float*)alloc((size_t)LL * BB * 2048 * 4);
  float* stab = (float*)alloc((size_t)SS * 32 * 4);
  float* ctab = (float*)alloc((size_t)SS * 32 * 4);
  u16* xb    = (u16*)alloc((size_t)NTOK * 2048 * 2);
  u16* h     = (u16*)alloc((size_t)NTOK * DD * 2);   // bf16 residual stream
  u16* units = (u16*)alloc((size_t)NTOK * DD * 2);
  u16* projq = (u16*)alloc((size_t)NTOK * QKVW * 2);
  u16* qrb   = (u16*)alloc((size_t)NTOK * DD * 2);
  u16* krb   = (u16*)alloc((size_t)NTOK * DD * 2);
  u16* vtb   = (u16*)alloc((size_t)NTOK * DD * 2);
  u16* acat  = (u16*)alloc((size_t)NTOK * CATW * 2);
  u16* hn    = (u16*)alloc((size_t)NTOK * DD * 2);
  float* ob  = (float*)alloc((size_t)NTOK * EE * 4);

  auto castN = [&](const float* src, u16* dst, size_t n) {
    const size_t n4 = n / 4;
    cast_bf16<<<dim3((unsigned)((n4 + 255) / 256)), dim3(256), 0, stream>>>(src, dst, n4);
  };
  castN(in_w, in_w_h, (size_t)DD * 2048);
  cast_q<<<dim3(QKVW * 128 / 256, LL), 256, 0, stream>>>(proj_w, qf_w_h);
  cast_ffg<<<dim3(8192 * 128 / 256, LL), 256, 0, stream>>>(proj_w, qf_w_h);
  cast_catw<<<dim3(DD * 640 / 256, LL), 256, 0, stream>>>(attn_w, ff_w, cat_w_h);
  add_bias<<<dim3(LL * DD / 256), 256, 0, stream>>>(attn_b, ff_b, cat_b, LL * DD);
  castN(out_w, out_w_h, (size_t)EE * DD);

  time_fourier<<<dim3(2, BB), 256, 0, stream>>>(times, fourier, te0);
  vec_gemm<0, 1><<<dim3(4, BB, 1), 256, 0, stream>>>(te0, t1_w, t1_b, te1, 1024, 1024);
  vec_gemm<0, 0><<<dim3(4, BB, 1), 256, 0, stream>>>(te1, t2_w, t2_b, te2, 1024, 1024);
  vec_gemm<1, 0><<<dim3(8, BB, LL), 256, 0, stream>>>(te2, cond_w, cond_b, sb, 2048, 1024);
  rope_tab<<<SS, 32, 0, stream>>>(stab, ctab);
  build_x<<<16384, 256, 0, stream>>>(noisy, condi, prev, infill, xb);
  gemm_bt<0, 1><<<dim3(DD / 128, NTOK / 128), 256, 0, stream>>>(xb, in_w_h, in_b, h, NTOK, DD, 2048);

  for (int l = 0; l < LL; l++) {
    ln_mod<<<NTOK, 256, 0, stream>>>(h, ln_w + (size_t)l * DD, ln_b + (size_t)l * DD,
                                     sb + (size_t)l * BB * 2048, units);
    gemm_qf256<<<dim3(FUSED / 256, NTOK / 256), 512, 0, stream>>>(
        units, qf_w_h + (size_t)l * FUSED * DD, projq, acat, NTOK, DD);
    rope_all<<<dim3(SS / 64, HH, BB), 256, 0, stream>>>(projq, stab, ctab, qrb, krb, vtb);
    attn_fwd<<<dim3(2048), 256, 0, stream>>>(qrb, krb, vtb, amask, acat);
    gemm_bt<1, 0><<<dim3(DD / 128, NTOK / 128), 256, 0, stream>>>(
        acat, cat_w_h + (size_t)l * DD * CATW, cat_b + (size_t)l * DD, h, NTOK, DD, CATW);
  }

  ln_mod<<<NTOK, 256, 0, stream>>>(h, outln_w, outln_b, nullptr, hn);
  gemm_bt<0, 0><<<dim3(EE / 128, NTOK / 128), 256, 0, stream>>>(hn, out_w_h, out_b, ob, NTOK, EE, DD);
  ln_fin<<<NTOK, 128, 0, stream>>>(ob, fin_w, fin_b, outp);
}

// Round 15
// 4485.371 us; speedup vs baseline: 1.0368x; 1.0021x over previous
//
#include <hip/hip_runtime.h>
#include <hip/hip_bf16.h>
#include <cstddef>
#include <cstdint>

// Problem constants
#define BB 8
#define SS 1024
#define EE 512
#define DD 1024
#define LL 8
#define HH 16
#define HD 64
#define ROT 32
#define FF 4096
#define FUSED 11264   // 3*D + 2*FF
#define NTOK 8192     // B*S
#define QKVW 3072     // width of qkv projection buffer
#define CATW 5120     // attn-out (1024) + gated-ff (4096) concat width

using u16 = unsigned short;
typedef __attribute__((ext_vector_type(8))) __bf16 bf16x8;
typedef __attribute__((ext_vector_type(4))) float f32x4;
typedef __attribute__((ext_vector_type(4))) unsigned short u16x4;
typedef __attribute__((ext_vector_type(8))) unsigned short u16x8;

typedef const __attribute__((address_space(1))) void gas_t;
typedef __attribute__((address_space(3))) void las_t;

#define VMCNT8 asm volatile("s_waitcnt vmcnt(8)" ::: "memory")
#define VMCNT0 asm volatile("s_waitcnt vmcnt(0)" ::: "memory")

__device__ __forceinline__ void gld16(const void* g, void* l) {
  __builtin_amdgcn_global_load_lds((gas_t*)g, (las_t*)l, 16, 0, 0);
}

__device__ __forceinline__ float bf2f(u16 u) {
  union { unsigned int i; float f; } v; v.i = ((unsigned int)u) << 16; return v.f;
}
__device__ __forceinline__ u16 f2bf(float f) {
  union { float f; unsigned int i; } v; v.f = f;
  unsigned int u = v.i;
  unsigned int r = u + 0x7FFFu + ((u >> 16) & 1u);
  return (u16)(r >> 16);
}
__device__ __forceinline__ float gelu_f(float x) {
  return x * 0.5f * (1.0f + erff(x / 1.41421f));
}
__device__ __forceinline__ float silu_f(float x) {
  return x / (1.0f + __expf(-x));
}

// ---------------------------------------------------------------------------
// Generic bf16 B^T GEMM: C[M,N] (+)= A[M,K] * W[N,K]^T (+ bias[N])
// 128x128 tile, BK=64, 4 waves (2x2). Counted-vmcnt two-barrier K-loop.
// ACCUM=1: bf16 read-modify-write (residual stream h is bf16).
// ---------------------------------------------------------------------------
template <int ACCUM, int OUTBF16>
__global__ __launch_bounds__(256, 2) void gemm_bt(
    const u16* __restrict__ A, const u16* __restrict__ W,
    const float* __restrict__ bias, void* __restrict__ Cp,
    int M, int N, int K) {
  __shared__ __align__(16) u16 As[2][128 * 64];
  __shared__ __align__(16) u16 Bs[2][128 * 64];
  const int tid = threadIdx.x;
  const int w = tid >> 6, lane = tid & 63;
  const int m0 = blockIdx.y * 128, n0 = blockIdx.x * 128;
  const int wm = w >> 1, wn = w & 1;

  f32x4 acc[4][4] = {};

  auto stage = [&](int buf, int k0) {
#pragma unroll
    for (int i = 0; i < 4; i++) {
      const int c = w + i * 4;                 // 1KB chunk id, 0..15
      const int r = c * 8 + (lane >> 3);       // tile row (128B rows)
      const int colb = ((lane & 7) << 4) ^ ((r & 7) << 4);  // pre-swizzled src col
      gld16(A + (size_t)(m0 + r) * K + k0 + (colb >> 1), &As[buf][c * 512]);
      gld16(W + (size_t)(n0 + r) * K + k0 + (colb >> 1), &Bs[buf][c * 512]);
    }
  };

  const int nt = K >> 6;
  stage(0, 0);

  for (int t = 0; t < nt; t++) {
    const int cur = t & 1;
    if (t + 1 < nt) {
      stage(cur ^ 1, (t + 1) << 6);
      VMCNT8;
    } else {
      VMCNT0;
    }
    __builtin_amdgcn_s_barrier();   // buf[cur] published (all waves)

    bf16x8 av0[4], bv0[4], av1[4], bv1[4];
#pragma unroll
    for (int m = 0; m < 4; m++) {
      const int row = wm * 64 + m * 16 + (lane & 15);
      const int sw = (row & 7) << 4;
      av0[m] = *(const bf16x8*)((const char*)As[cur] + row * 128 + ((((lane >> 4) << 4)) ^ sw));
      av1[m] = *(const bf16x8*)((const char*)As[cur] + row * 128 + ((64 + ((lane >> 4) << 4)) ^ sw));
    }
#pragma unroll
    for (int n = 0; n < 4; n++) {
      const int row = wn * 64 + n * 16 + (lane & 15);
      const int sw = (row & 7) << 4;
      bv0[n] = *(const bf16x8*)((const char*)Bs[cur] + row * 128 + ((((lane >> 4) << 4)) ^ sw));
      bv1[n] = *(const bf16x8*)((const char*)Bs[cur] + row * 128 + ((64 + ((lane >> 4) << 4)) ^ sw));
    }
    __builtin_amdgcn_s_setprio(1);
#pragma unroll
    for (int m = 0; m < 4; m++)
#pragma unroll
      for (int n = 0; n < 4; n++)
        acc[m][n] = __builtin_amdgcn_mfma_f32_16x16x32_bf16(av0[m], bv0[n], acc[m][n], 0, 0, 0);
#pragma unroll
    for (int m = 0; m < 4; m++)
#pragma unroll
      for (int n = 0; n < 4; n++)
        acc[m][n] = __builtin_amdgcn_mfma_f32_16x16x32_bf16(av1[m], bv1[n], acc[m][n], 0, 0, 0);
    __builtin_amdgcn_s_setprio(0);
    __builtin_amdgcn_s_barrier();   // buf[cur] free for overwrite next iter
  }

  const int rowb0 = m0 + wm * 64 + ((lane >> 4) << 2);
  const int colb0 = n0 + wn * 64 + (lane & 15);
#pragma unroll
  for (int n = 0; n < 4; n++) {
    const int col = colb0 + n * 16;
    const float bn = bias ? bias[col] : 0.0f;
#pragma unroll
    for (int m = 0; m < 4; m++) {
#pragma unroll
      for (int r = 0; r < 4; r++) {
        const size_t idx = (size_t)(rowb0 + m * 16 + r) * N + col;
        const float v = acc[m][n][r] + bn;
        if (ACCUM) {
          u16* c = (u16*)Cp;
          c[idx] = f2bf(bf2f(c[idx]) + v);   // bf16 residual RMW
        } else if (OUTBF16) {
          ((u16*)Cp)[idx] = f2bf(v);
        } else {
          ((float*)Cp)[idx] = v;
        }
      }
    }
  }
}

// ---------------------------------------------------------------------------
// Merged qkv+ffg 256x256-tile bf16 B^T GEMM (8 waves 2Mx4N, BK=64, 128KB LDS
// dbuf, counted-vmcnt two-barrier pipeline). Weight rows [0,3072) = qkv;
// rows [3072,11264) = ff/gate interleaved per 16-col group. Epilogue branches
// on wave-uniform n0: qkv -> projq; gated -> acat cols [1024,5120).
// ---------------------------------------------------------------------------
__global__ __launch_bounds__(512, 2) void gemm_qf256(
    const u16* __restrict__ A, const u16* __restrict__ W,
    u16* __restrict__ projq, u16* __restrict__ acat, int M, int K) {
  __shared__ __align__(16) u16 As[2][256 * 64];   // 64 KB
  __shared__ __align__(16) u16 Bs[2][256 * 64];   // 64 KB
  const int tid = threadIdx.x;
  const int w = tid >> 6, lane = tid & 63;
  const int m0 = blockIdx.y * 256, n0 = blockIdx.x * 256;
  const int wm = w >> 2, wn = w & 3;   // 2 x 4 wave grid

  f32x4 acc[8][4] = {};

  auto stage = [&](int buf, int k0) {
#pragma unroll
    for (int i = 0; i < 4; i++) {
      const int c = w + i * 8;                 // 1KB chunk id, 0..31
      const int r = c * 8 + (lane >> 3);       // tile row 0..255 (128B rows)
      const int colb = ((lane & 7) << 4) ^ ((r & 7) << 4);
      gld16(A + (size_t)(m0 + r) * K + k0 + (colb >> 1), &As[buf][c * 512]);
      gld16(W + (size_t)(n0 + r) * K + k0 + (colb >> 1), &Bs[buf][c * 512]);
    }
  };

  const int nt = K >> 6;
  stage(0, 0);

  for (int t = 0; t < nt; t++) {
    const int cur = t & 1;
    if (t + 1 < nt) {
      stage(cur ^ 1, (t + 1) << 6);
      VMCNT8;
    } else {
      VMCNT0;
    }
    __builtin_amdgcn_s_barrier();

    // ks=0
    {
      bf16x8 av0[8], bv0[4];
#pragma unroll
      for (int m = 0; m < 8; m++) {
        const int row = wm * 128 + m * 16 + (lane & 15);
        const int cb = (((lane >> 4) << 4)) ^ ((row & 7) << 4);
        av0[m] = *(const bf16x8*)((const char*)As[cur] + row * 128 + cb);
      }
#pragma unroll
      for (int n = 0; n < 4; n++) {
        const int row = wn * 64 + n * 16 + (lane & 15);
        const int cb = (((lane >> 4) << 4)) ^ ((row & 7) << 4);
        bv0[n] = *(const bf16x8*)((const char*)Bs[cur] + row * 128 + cb);
      }
      __builtin_amdgcn_s_setprio(1);
#pragma unroll
      for (int m = 0; m < 8; m++)
#pragma unroll
        for (int n = 0; n < 4; n++)
          acc[m][n] = __builtin_amdgcn_mfma_f32_16x16x32_bf16(av0[m], bv0[n], acc[m][n], 0, 0, 0);
      __builtin_amdgcn_s_setprio(0);
    }
    // ks=1
    {
      bf16x8 av1[8], bv1[4];
#pragma unroll
      for (int m = 0; m < 8; m++) {
        const int row = wm * 128 + m * 16 + (lane & 15);
        const int cb = (64 + ((lane >> 4) << 4)) ^ ((row & 7) << 4);
        av1[m] = *(const bf16x8*)((const char*)As[cur] + row * 128 + cb);
      }
#pragma unroll
      for (int n = 0; n < 4; n++) {
        const int row = wn * 64 + n * 16 + (lane & 15);
        const int cb = (64 + ((lane >> 4) << 4)) ^ ((row & 7) << 4);
        bv1[n] = *(const bf16x8*)((const char*)Bs[cur] + row * 128 + cb);
      }
      __builtin_amdgcn_s_setprio(1);
#pragma unroll
      for (int m = 0; m < 8; m++)
#pragma unroll
        for (int n = 0; n < 4; n++)
          acc[m][n] = __builtin_amdgcn_mfma_f32_16x16x32_bf16(av1[m], bv1[n], acc[m][n], 0, 0, 0);
      __builtin_amdgcn_s_setprio(0);
    }
    __builtin_amdgcn_s_barrier();
  }

  const int rowb0 = m0 + wm * 128 + ((lane >> 4) << 2);
  if (n0 >= QKVW) {
    const int ocol0 = DD + ((n0 - QKVW) >> 1);
#pragma unroll
    for (int n = 0; n < 4; n += 2) {
      const int outcol = ocol0 + wn * 32 + ((n >> 1) << 4) + (lane & 15);
#pragma unroll
      for (int m = 0; m < 8; m++)
#pragma unroll
        for (int r = 0; r < 4; r++) {
          const float fv = acc[m][n][r];
          const float gv = acc[m][n + 1][r];
          acat[(size_t)(rowb0 + m * 16 + r) * CATW + outcol] = f2bf(fv * gelu_f(gv));
        }
    }
  } else {
    const int colb0 = n0 + wn * 64 + (lane & 15);
#pragma unroll
    for (int n = 0; n < 4; n++) {
      const int col = colb0 + n * 16;
#pragma unroll
      for (int m = 0; m < 8; m++)
#pragma unroll
        for (int r = 0; r < 4; r++)
          projq[(size_t)(rowb0 + m * 16 + r) * QKVW + col] = f2bf(acc[m][n][r]);
    }
  }
}

// ---------------------------------------------------------------------------
// Flash attention: swapped QK^T, tree row-max, T13 defer-max, T12 cvt_pk.
// Output into acat cols [0,1024), row stride CATW.  (R13-verified version.)
// ---------------------------------------------------------------------------
__global__ __launch_bounds__(256, 2) void attn_fwd(
    const u16* __restrict__ qr, const u16* __restrict__ kr,
    const u16* __restrict__ vt, const float* __restrict__ mask,
    u16* __restrict__ acat) {
  __shared__ __align__(16) u16 Ks[2][128 * 64];   // [key][dim], swizzled
  __shared__ __align__(16) u16 Vs[2][64 * 128];   // [d][key], swizzled
  __shared__ __align__(16) u16 Ps[4][16 * 128];   // per-wave P [q][k], XOR-swizzled
  const int tid = threadIdx.x, w = tid >> 6, lane = tid & 63;
  const int g = blockIdx.x;
  const int j = g >> 3;
  const int bh = (g & 7) + ((j >> 4) << 3);
  const int qx = j & 15;
  const int b = bh >> 4;
  const int q0 = qx * 64 + w * 16;
  const u16* Qb = qr + (size_t)bh * SS * HD;
  const u16* Kb = kr + (size_t)bh * SS * HD;
  const u16* Vb = vt + (size_t)bh * HD * SS;
  const float* mb = mask + (size_t)b * SS;
  const int lq = lane & 15, lg = lane >> 4;

  bf16x8 qf0, qf1;
  {
    const int qrow = q0 + lq;
    const u16* qp = Qb + (size_t)qrow * HD + (lg << 3);
    qf0 = *(const bf16x8*)qp;
    qf1 = *(const bf16x8*)(qp + 32);
  }

  float mrun = -1e30f, srun = 0.0f;   // running stats for q-row = lq
  f32x4 acc[4] = {};

  u16* pw = &Ps[w][0];

  auto stage = [&](int buf, int kv0) {
#pragma unroll
    for (int i = 0; i < 4; i++) {
      const int c = w + i * 4;
      {
        const int r = c * 8 + (lane >> 3);
        const int colb = ((lane & 7) << 4) ^ ((r & 7) << 4);
        gld16(Kb + (size_t)(kv0 + r) * HD + (colb >> 1), &Ks[buf][c * 512]);
      }
      {
        const int d = c * 4 + lg;
        const int colb = (lq << 4) ^ ((d & 7) << 4);
        gld16(Vb + (size_t)d * SS + kv0 + (colb >> 1), &Vs[buf][c * 512]);
      }
    }
  };

  stage(0, 0);
  __syncthreads();

  for (int t = 0; t < 8; t++) {
    const int cur = t & 1;
    const int kv0 = t * 128;
    if (t < 7) stage(cur ^ 1, kv0 + 128);

    // swapped QK^T: p[blk][r] = P[key = blk*16 + lg*4 + r][q = lq]
    f32x4 p[8];
    __builtin_amdgcn_s_setprio(1);
#pragma unroll
    for (int blk = 0; blk < 8; blk++) {
      const int row = blk * 16 + lq;
      const int swz = (row & 7) << 4;
      const bf16x8 k0v = *(const bf16x8*)((const char*)Ks[cur] + row * 128 + (((lg << 4)) ^ swz));
      const bf16x8 k1v = *(const bf16x8*)((const char*)Ks[cur] + row * 128 + ((64 + (lg << 4)) ^ swz));
      f32x4 z = {};
      p[blk] = __builtin_amdgcn_mfma_f32_16x16x32_bf16(k0v, qf0, z, 0, 0, 0);
      p[blk] = __builtin_amdgcn_mfma_f32_16x16x32_bf16(k1v, qf1, p[blk], 0, 0, 0);
    }
    __builtin_amdgcn_s_setprio(0);

#pragma unroll
    for (int blk = 0; blk < 8; blk++) {
      const float4 m4 = *(const float4*)(mb + kv0 + blk * 16 + (lg << 2));
      p[blk][0] = p[blk][0] * (1.0f / 64.0f) + m4.x;
      p[blk][1] = p[blk][1] * (1.0f / 64.0f) + m4.y;
      p[blk][2] = p[blk][2] * (1.0f / 64.0f) + m4.z;
      p[blk][3] = p[blk][3] * (1.0f / 64.0f) + m4.w;
    }

    // tree row-max (shallow dependency chains)
    float mr[8];
#pragma unroll
    for (int blk = 0; blk < 8; blk++)
      mr[blk] = fmaxf(fmaxf(p[blk][0], p[blk][1]), fmaxf(p[blk][2], p[blk][3]));
    float mrow = fmaxf(fmaxf(fmaxf(mr[0], mr[1]), fmaxf(mr[2], mr[3])),
                       fmaxf(fmaxf(mr[4], mr[5]), fmaxf(mr[6], mr[7])));
    mrow = fmaxf(mrow, __shfl_xor(mrow, 16));
    mrow = fmaxf(mrow, __shfl_xor(mrow, 32));

    if (__any(mrow > mrun)) {       // T13 defer-max (exact at THR=0)
      const float mn = fmaxf(mrun, mrow);
      const float facq = __expf(mrun - mn);
      mrun = mn;
      srun *= facq;
      float fac[4];
#pragma unroll
      for (int r = 0; r < 4; r++)
        fac[r] = __shfl(facq, (lane & 48) | ((lg << 2) + r));
#pragma unroll
      for (int dblk = 0; dblk < 4; dblk++)
#pragma unroll
        for (int r = 0; r < 4; r++) acc[dblk][r] *= fac[r];
    }

    // exp + 4-way parallel sum + cvt_pk bf16 pack (T12)
    float rs0 = 0.0f, rs1 = 0.0f, rs2 = 0.0f, rs3 = 0.0f;
#pragma unroll
    for (int blk = 0; blk < 8; blk++) {
      const float e0 = __expf(p[blk][0] - mrun);
      const float e1 = __expf(p[blk][1] - mrun);
      const float e2 = __expf(p[blk][2] - mrun);
      const float e3 = __expf(p[blk][3] - mrun);
      rs0 += e0; rs1 += e1; rs2 += e2; rs3 += e3;
      unsigned int r01, r23;
      asm("v_cvt_pk_bf16_f32 %0, %1, %2" : "=v"(r01) : "v"(e0), "v"(e1));
      asm("v_cvt_pk_bf16_f32 %0, %1, %2" : "=v"(r23) : "v"(e2), "v"(e3));
      uint2 pk; pk.x = r01; pk.y = r23;
      *(uint2*)(pw + ((lq * 128 + blk * 16 + (lg << 2)) ^ ((lq & 7) << 3))) = pk;
    }
    float rs = (rs0 + rs1) + (rs2 + rs3);
    rs += __shfl_xor(rs, 16);
    rs += __shfl_xor(rs, 32);
    srun += rs;

    bf16x8 pa[4];
#pragma unroll
    for (int ks = 0; ks < 4; ks++)
      pa[ks] = *(const bf16x8*)(pw + ((lq * 128 + ks * 32 + (lg << 3)) ^ ((lq & 7) << 3)));

    __builtin_amdgcn_s_setprio(1);
#pragma unroll
    for (int dblk = 0; dblk < 4; dblk++) {
      const int drow = dblk * 16 + lq;
      const int swz = (drow & 7) << 4;
#pragma unroll
      for (int ks = 0; ks < 4; ks++) {
        const bf16x8 vv = *(const bf16x8*)((const char*)Vs[cur] + drow * 256 + ((ks * 64 + (lg << 4)) ^ swz));
        acc[dblk] = __builtin_amdgcn_mfma_f32_16x16x32_bf16(pa[ks], vv, acc[dblk], 0, 0, 0);
      }
    }
    __builtin_amdgcn_s_setprio(0);

    __syncthreads();
  }

  float sden[4];
#pragma unroll
  for (int r = 0; r < 4; r++)
    sden[r] = __shfl(srun, (lane & 48) | ((lg << 2) + r));
#pragma unroll
  for (int dblk = 0; dblk < 4; dblk++)
#pragma unroll
    for (int r = 0; r < 4; r++) {
      const int sq = q0 + (lg << 2) + r;
      const int d = dblk * 16 + lq;
      acat[((size_t)b * SS + sq) * CATW + (bh & 15) * HD + d] = f2bf(acc[dblk][r] / sden[r]);
    }
}

// ---------------------------------------------------------------------------
// LayerNorm (+ optional AdaLN modulation) over D=1024, one block per row.
// Input h is bf16 (residual stream).
// ---------------------------------------------------------------------------
__global__ __launch_bounds__(256) void ln_mod(
    const u16* __restrict__ x, const float* __restrict__ lw,
    const float* __restrict__ lb, const float* __restrict__ sb,
    u16* __restrict__ out) {
  const int row = blockIdx.x, tid = threadIdx.x;
  const u16x4 hv = *(const u16x4*)(x + (size_t)row * DD + tid * 4);
  float vv[4] = {bf2f(hv[0]), bf2f(hv[1]), bf2f(hv[2]), bf2f(hv[3])};
  float s = vv[0] + vv[1] + vv[2] + vv[3];
  float q = vv[0] * vv[0] + vv[1] * vv[1] + vv[2] * vv[2] + vv[3] * vv[3];
  for (int off = 1; off < 64; off <<= 1) {
    s += __shfl_xor(s, off);
    q += __shfl_xor(q, off);
  }
  __shared__ float red[8];
  const int w = tid >> 6, lane = tid & 63;
  if (lane == 0) { red[w] = s; red[4 + w] = q; }
  __syncthreads();
  s = red[0] + red[1] + red[2] + red[3];
  q = red[4] + red[5] + red[6] + red[7];
  const float mu = s * (1.0f / DD);
  const float inv = rsqrtf(q * (1.0f / DD) - mu * mu + 1e-5f);
  const int b = row >> 10;
  u16x4 o;
#pragma unroll
  for (int j = 0; j < 4; j++) {
    const int d = tid * 4 + j;
    float g = (vv[j] - mu) * inv * lw[d] + lb[d];
    if (sb) g = (1.0f + sb[(size_t)b * 2048 + d]) * g + sb[(size_t)b * 2048 + DD + d];
    o[j] = f2bf(g);
  }
  *(u16x4*)(out + (size_t)row * DD + tid * 4) = o;
}

// Final LayerNorm over E=512, f32 out. One block (128 threads) per row.
__global__ __launch_bounds__(128) void ln_fin(
    const float* __restrict__ x, const float* __restrict__ w_,
    const float* __restrict__ b_, float* __restrict__ out) {
  const int row = blockIdx.x, tid = threadIdx.x;
  const float4 v = ((const float4*)(x + (size_t)row * EE))[tid];
  float vv[4] = {v.x, v.y, v.z, v.w};
  float s = vv[0] + vv[1] + vv[2] + vv[3];
  float q = vv[0] * vv[0] + vv[1] * vv[1] + vv[2] * vv[2] + vv[3] * vv[3];
  for (int off = 1; off < 64; off <<= 1) {
    s += __shfl_xor(s, off);
    q += __shfl_xor(q, off);
  }
  __shared__ float red[4];
  const int w = tid >> 6, lane = tid & 63;
  if (lane == 0) { red[w] = s; red[2 + w] = q; }
  __syncthreads();
  s = red[0] + red[1];
  q = red[2] + red[3];
  const float mu = s * (1.0f / EE);
  const float inv = rsqrtf(q * (1.0f / EE) - mu * mu + 1e-5f);
  float4 o;
  o.x = (vv[0] - mu) * inv * w_[tid * 4 + 0] + b_[tid * 4 + 0];
  o.y = (vv[1] - mu) * inv * w_[tid * 4 + 1] + b_[tid * 4 + 1];
  o.z = (vv[2] - mu) * inv * w_[tid * 4 + 2] + b_[tid * 4 + 2];
  o.w = (vv[3] - mu) * inv * w_[tid * 4 + 3] + b_[tid * 4 + 3];
  ((float4*)(out + (size_t)row * EE))[tid] = o;
}

template <int IA, int OA>
__global__ __launch_bounds__(256) void vec_gemm(
    const float* __restrict__ in, const float* __restrict__ W,
    const float* __restrict__ bias, float* __restrict__ out, int N, int K) {
  const int n = blockIdx.x * 256 + threadIdx.x;
  const int b = blockIdx.y, l = blockIdx.z;
  const float* ir = in + (size_t)b * K;
  const float* wr = W + ((size_t)l * N + n) * K;
  float s = bias[(size_t)l * N + n];
  for (int k = 0; k < K; k += 4) {
    float4 a = *(const float4*)(ir + k);
    const float4 ww = *(const float4*)(wr + k);
    if (IA) { a.x = silu_f(a.x); a.y = silu_f(a.y); a.z = silu_f(a.z); a.w = silu_f(a.w); }
    s += a.x * ww.x + a.y * ww.y + a.z * ww.z + a.w * ww.w;
  }
  if (OA) s = gelu_f(s);
  out[((size_t)l * gridDim.y + b) * N + n] = s;
}

__global__ void time_fourier(const float* __restrict__ times,
                             const float* __restrict__ fw, float* __restrict__ te0) {
  const int j = blockIdx.x * 256 + threadIdx.x;
  const int b = blockIdx.y;
  const float f = 6.28318530717958647692f * times[b] * fw[j];
  te0[(size_t)b * DD + j] = cosf(f);
  te0[(size_t)b * DD + 512 + j] = sinf(f);
}

__global__ void rope_tab(float* __restrict__ st, float* __restrict__ ct) {
  const int s = blockIdx.x;
  const int j = threadIdx.x;
  const int i = j & 15;
  const float inv = powf(10000.0f, -(float)i * (1.0f / 16.0f));
  const float f = (float)s * inv;
  st[s * 32 + j] = bf2f(f2bf(sinf(f)));
  ct[s * 32 + j] = bf2f(f2bf(cosf(f)));
}

__global__ void build_x(const float* __restrict__ a, const float* __restrict__ b,
                        const float* __restrict__ c, const float* __restrict__ m,
                        u16* __restrict__ x) {
  const size_t i4 = ((size_t)blockIdx.x * 256 + threadIdx.x) * 4;
  if (i4 >= (size_t)NTOK * 2048) return;
  const size_t tok = i4 >> 11;
  const int e = (int)(i4 & 2047);
  float4 v;
  if (e < 512)       v = *(const float4*)(a + tok * 512 + e);
  else if (e < 1024) v = *(const float4*)(b + tok * 512 + (e - 512));
  else if (e < 1536) v = *(const float4*)(c + tok * 512 + (e - 1024));
  else { const float mm = m[tok]; v = make_float4(mm, mm, mm, mm); }
  u16x4 o;
  o[0] = f2bf(v.x); o[1] = f2bf(v.y); o[2] = f2bf(v.z); o[3] = f2bf(v.w);
  *(u16x4*)(x + i4) = o;
}

// ---------------------------------------------------------------------------
// Fused RoPE(q,k) + head-split + V-transpose. grid (S/64, H, B), 256 threads.
// ---------------------------------------------------------------------------
__global__ __launch_bounds__(256) void rope_all(
    const u16* __restrict__ proj, const float* __restrict__ st,
    const float* __restrict__ ct, u16* __restrict__ q, u16* __restrict__ k,
    u16* __restrict__ v) {
  __shared__ u16 tile[4 * 1160];
  const int tid = threadIdx.x;
  const int s0 = blockIdx.x * 64, h = blockIdx.y, b = blockIdx.z;
  const int sl = tid >> 2, c = tid & 3;
  const int s = s0 + sl;
  const u16* pr = proj + (size_t)(b * SS + s) * QKVW + h * 64;

  {
    const u16x8 a0 = *(const u16x8*)(pr + 2 * DD + c * 16);
    const u16x8 a1 = *(const u16x8*)(pr + 2 * DD + c * 16 + 8);
    u16* trow = &tile[(sl >> 4) * 1160 + (sl & 15) * 72];
    *(u16x8*)&trow[c * 16] = a0;
    *(u16x8*)&trow[c * 16 + 8] = a1;
  }

  {
    const int d0 = c * 16;
    u16 qv[16], kv[16], qo[16], ko[16];
    *(u16x8*)&qv[0] = *(const u16x8*)(pr + d0);
    *(u16x8*)&qv[8] = *(const u16x8*)(pr + d0 + 8);
    *(u16x8*)&kv[0] = *(const u16x8*)(pr + DD + d0);
    *(u16x8*)&kv[8] = *(const u16x8*)(pr + DD + d0 + 8);
    if (c < 2) {
      const int dp = (c ^ 1) * 16;
      u16 qp[16], kp[16];
      *(u16x8*)&qp[0] = *(const u16x8*)(pr + dp);
      *(u16x8*)&qp[8] = *(const u16x8*)(pr + dp + 8);
      *(u16x8*)&kp[0] = *(const u16x8*)(pr + DD + dp);
      *(u16x8*)&kp[8] = *(const u16x8*)(pr + DD + dp + 8);
      const float sg = (c == 0) ? -1.0f : 1.0f;
#pragma unroll
      for (int j = 0; j < 16; j++) {
        const int d = d0 + j;
        const float cs = ct[s * 32 + d], sn = st[s * 32 + d];
        qo[j] = f2bf(bf2f(qv[j]) * cs + sg * bf2f(qp[j]) * sn);
        ko[j] = f2bf(bf2f(kv[j]) * cs + sg * bf2f(kp[j]) * sn);
      }
    } else {
#pragma unroll
      for (int j = 0; j < 16; j++) { qo[j] = qv[j]; ko[j] = kv[j]; }
    }
    u16* qd = q + ((size_t)(b * HH + h) * SS + s) * HD + d0;
    u16* kd = k + ((size_t)(b * HH + h) * SS + s) * HD + d0;
    *(u16x8*)qd = *(u16x8*)&qo[0];
    *(u16x8*)(qd + 8) = *(u16x8*)&qo[8];
    *(u16x8*)kd = *(u16x8*)&ko[0];
    *(u16x8*)(kd + 8) = *(u16x8*)&ko[8];
  }

  __syncthreads();

  {
    const int dl = tid >> 2, gq = tid & 3;   // qs = gq*16
    const u16* tg = &tile[gq * 1160];
    u16x8 o0, o1;
#pragma unroll
    for (int j = 0; j < 8; j++) o0[j] = tg[j * 72 + dl];
#pragma unroll
    for (int j = 0; j < 8; j++) o1[j] = tg[(8 + j) * 72 + dl];
    u16* dst = v + ((size_t)(b * HH + h) * HD + dl) * SS + s0 + gq * 16;
    *(u16x8*)dst = o0;
    *(u16x8*)(dst + 8) = o1;
  }
}

__global__ void cast_bf16(const float* __restrict__ in, u16* __restrict__ out, size_t n4) {
  const size_t i = (size_t)blockIdx.x * 256 + threadIdx.x;
  if (i >= n4) return;
  const float4 v = ((const float4*)in)[i];
  u16x4 o;
  o[0] = f2bf(v.x); o[1] = f2bf(v.y); o[2] = f2bf(v.z); o[3] = f2bf(v.w);
  ((u16x4*)out)[i] = o;
}

// qkv slice of proj_w -> rows [0,3072) of the merged [11264][1024] buffer.
__global__ void cast_q(const float* __restrict__ src, u16* __restrict__ dst) {
  const int i = blockIdx.x * 256 + threadIdx.x;  // over 3072*128
  const int l = blockIdx.y;
  const int r = i >> 7, cb = (i & 127) * 8;
  const float* s = src + ((size_t)l * FUSED + r) * DD + cb;
  const float4 a = *(const float4*)s;
  const float4 b = *(const float4*)(s + 4);
  u16x8 o;
  o[0] = f2bf(a.x); o[1] = f2bf(a.y); o[2] = f2bf(a.z); o[3] = f2bf(a.w);
  o[4] = f2bf(b.x); o[5] = f2bf(b.y); o[6] = f2bf(b.z); o[7] = f2bf(b.w);
  *(u16x8*)(dst + ((size_t)l * FUSED + r) * DD + cb) = o;
}

// ff/gate interleaved slice -> rows [3072,11264) of the merged buffer.
__global__ void cast_ffg(const float* __restrict__ src, u16* __restrict__ dst) {
  const int i = blockIdx.x * 256 + threadIdx.x;  // over 8192*128
  const int l = blockIdx.y;
  const int r = i >> 7, cb = (i & 127) * 8;
  const int t16 = r >> 4, pos = r & 15;
  const int j = (t16 >> 1) * 16 + pos;
  const int srow = (t16 & 1) ? (3 * DD + FF + j) : (3 * DD + j);
  const float* s = src + ((size_t)l * FUSED + srow) * DD + cb;
  const float4 a = *(const float4*)s;
  const float4 b = *(const float4*)(s + 4);
  u16x8 o;
  o[0] = f2bf(a.x); o[1] = f2bf(a.y); o[2] = f2bf(a.z); o[3] = f2bf(a.w);
  o[4] = f2bf(b.x); o[5] = f2bf(b.y); o[6] = f2bf(b.z); o[7] = f2bf(b.w);
  *(u16x8*)(dst + ((size_t)l * FUSED + QKVW + r) * DD + cb) = o;
}

__global__ void cast_catw(const float* __restrict__ aw, const float* __restrict__ fw,
                          u16* __restrict__ dst) {
  const int i = blockIdx.x * 256 + threadIdx.x;  // over DD*640
  const int l = blockIdx.y;
  const int n = i / 640, cb = (i % 640) * 8;
  const float* s = (cb < DD) ? (aw + ((size_t)l * DD + n) * DD + cb)
                             : (fw + ((size_t)l * DD + n) * FF + (cb - DD));
  const float4 a = *(const float4*)s;
  const float4 b = *(const float4*)(s + 4);
  u16x8 o;
  o[0] = f2bf(a.x); o[1] = f2bf(a.y); o[2] = f2bf(a.z); o[3] = f2bf(a.w);
  o[4] = f2bf(b.x); o[5] = f2bf(b.y); o[6] = f2bf(b.z); o[7] = f2bf(b.w);
  *(u16x8*)(dst + ((size_t)l * DD + n) * CATW + cb) = o;
}

__global__ void add_bias(const float* __restrict__ a, const float* __restrict__ b,
                         float* __restrict__ o, int n) {
  const int i = blockIdx.x * 256 + threadIdx.x;
  if (i < n) o[i] = a[i] + b[i];
}

// ---------------------------------------------------------------------------
extern "C" void kernel_launch(void* const* d_in, const int* in_sizes, int n_in,
                              void* d_out, int out_size, void* d_ws, size_t ws_size,
                              hipStream_t stream) {
  const float* noisy   = (const float*)d_in[0];
  const float* condi   = (const float*)d_in[1];
  const float* prev    = (const float*)d_in[2];
  const float* infill  = (const float*)d_in[3];
  const float* amask   = (const float*)d_in[4];
  const float* times   = (const float*)d_in[5];
  const float* fourier = (const float*)d_in[6];
  const float* t1_w    = (const float*)d_in[7];
  const float* t1_b    = (const float*)d_in[8];
  const float* t2_w    = (const float*)d_in[9];
  const float* t2_b    = (const float*)d_in[10];
  const float* in_w    = (const float*)d_in[11];
  const float* in_b    = (const float*)d_in[12];
  const float* ln_w    = (const float*)d_in[13];
  const float* ln_b    = (const float*)d_in[14];
  const float* cond_w  = (const float*)d_in[15];
  const float* cond_b  = (const float*)d_in[16];
  const float* proj_w  = (const float*)d_in[17];
  const float* attn_w  = (const float*)d_in[18];
  const float* attn_b  = (const float*)d_in[19];
  const float* ff_w    = (const float*)d_in[20];
  const float* ff_b    = (const float*)d_in[21];
  const float* outln_w = (const float*)d_in[22];
  const float* outln_b = (const float*)d_in[23];
  const float* out_w   = (const float*)d_in[24];
  const float* out_b   = (const float*)d_in[25];
  const float* fin_w   = (const float*)d_in[26];
  const float* fin_b   = (const float*)d_in[27];
  float* outp = (float*)d_out;

  char* p = (char*)d_ws;
  auto alloc = [&](size_t bytes) -> char* {
    char* r = p;
    p += (bytes + 255) & ~(size_t)255;
    return r;
  };
  u16* in_w_h    = (u16*)alloc((size_t)DD * 2048 * 2);
  u16* qf_w_h    = (u16*)alloc((size_t)LL * FUSED * DD * 2);   // merged qkv+ffg weights
  u16* cat_w_h   = (u16*)alloc((size_t)LL * DD * CATW * 2);
  float* cat_b   = (float*)alloc((size_t)LL * DD * 4);
  u16* out_w_h   = (u16*)alloc((size_t)EE * DD * 2);
  float* te0 = (float*)alloc((size_t)BB * DD * 4);
  float* te1 = (float*)alloc((size_t)BB * DD * 4);
  float* te2 = (float*)alloc((size_t)BB * DD * 4);
  float* sb  = (float*)alloc((size_t)LL * BB * 2048 * 4);
  float* stab = (float*)alloc((size_t)SS * 32 * 4);
  float* ctab = (float*)alloc((size_t)SS * 32 * 4);
  u16* xb    = (u16*)alloc((size_t)NTOK * 2048 * 2);
  u16* h     = (u16*)alloc((size_t)NTOK * DD * 2);   // bf16 residual stream
  u16* units = (u16*)alloc((size_t)NTOK * DD * 2);
  u16* projq = (u16*)alloc((size_t)NTOK * QKVW * 2);
  u16* qrb   = (u16*)alloc((size_t)NTOK * DD * 2);
  u16* krb   = (u16*)alloc((size_t)NTOK * DD * 2);
  u16* vtb   = (u16*)alloc((size_t)NTOK * DD * 2);
  u16* acat  = (u16*)alloc((size_t)NTOK * CATW * 2);
  u16* hn    = (u16*)alloc((size_t)NTOK * DD * 2);
  float* ob  = (float*)alloc((size_t)NTOK * EE * 4);

  auto castN = [&](const float* src, u16* dst, size_t n) {
    const size_t n4 = n / 4;
    cast_bf16<<<dim3((unsigned)((n4 + 255) / 256)), dim3(256), 0, stream>>>(src, dst, n4);
  };
  castN(in_w, in_w_h, (size_t)DD * 2048);
  cast_q<<<dim3(QKVW * 128 / 256, LL), 256, 0, stream>>>(proj_w, qf_w_h);
  cast_ffg<<<dim3(8192 * 128 / 256, LL), 256, 0, stream>>>(proj_w, qf_w_h);
  cast_catw<<<dim3(DD * 640 / 256, LL), 256, 0, stream>>>(attn_w, ff_w, cat_w_h);
  add_bias<<<dim3(LL * DD / 256), 256, 0, stream>>>(attn_b, ff_b, cat_b, LL * DD);
  castN(out_w, out_w_h, (size_t)EE * DD);

  time_fourier<<<dim3(2, BB), 256, 0, stream>>>(times, fourier, te0);
  vec_gemm<0, 1><<<dim3(4, BB, 1), 256, 0, stream>>>(te0, t1_w, t1_b, te1, 1024, 1024);
  vec_gemm<0, 0><<<dim3(4, BB, 1), 256, 0, stream>>>(te1, t2_w, t2_b, te2, 1024, 1024);
  vec_gemm<1, 0><<<dim3(8, BB, LL), 256, 0, stream>>>(te2, cond_w, cond_b, sb, 2048, 1024);
  rope_tab<<<SS, 32, 0, stream>>>(stab, ctab);
  build_x<<<16384, 256, 0, stream>>>(noisy, condi, prev, infill, xb);
  gemm_bt<0, 1><<<dim3(DD / 128, NTOK / 128), 256, 0, stream>>>(xb, in_w_h, in_b, h, NTOK, DD, 2048);

  for (int l = 0; l < LL; l++) {
    ln_mod<<<NTOK, 256, 0, stream>>>(h, ln_w + (size_t)l * DD, ln_b + (size_t)l * DD,
                                     sb + (size_t)l * BB * 2048, units);
    gemm_qf256<<<dim3(FUSED / 256, NTOK / 256), 512, 0, stream>>>(
        units, qf_w_h + (size_t)l * FUSED * DD, projq, acat, NTOK, DD);
    rope_all<<<dim3(SS / 64, HH, BB), 256, 0, stream>>>(projq, stab, ctab, qrb, krb, vtb);
    attn_fwd<<<dim3(2048), 256, 0, stream>>>(qrb, krb, vtb, amask, acat);
    gemm_bt<1, 0><<<dim3(DD / 128, NTOK / 128), 256, 0, stream>>>(
        acat, cat_w_h + (size_t)l * DD * CATW, cat_b + (size_t)l * DD, h, NTOK, DD, CATW);
  }

  ln_mod<<<NTOK, 256, 0, stream>>>(h, outln_w, outln_b, nullptr, hn);
  gemm_bt<0, 0><<<dim3(EE / 128, NTOK / 128), 256, 0, stream>>>(hn, out_w_h, out_b, ob, NTOK, EE, DD);
  ln_fin<<<NTOK, 128, 0, stream>>>(ob, fin_w, fin_b, outp);
}